// Round 10
// baseline (209.269 us; speedup 1.0000x reference)
//
#include <hip/hip_runtime.h>
#include <hip/hip_bf16.h>
#include <hip/hip_fp8.h>
#include <stdint.h>

// AutoInt: B=2048, F=64, D=128, H=8, P=64, V=100000 -- FP32 in/out.
// One block per batch element (grid 2048), 256 threads = 4 waves.
// Phase1 (projections) in FP8-e4m3 MFMA (e x64, W x8; 512x scale cancels),
// phase2/3 bf16 MFMA, softmax over the q axis. 2 barriers/head (proven
// minimum: q/k/att are cross-wave).
//
// Ledger: R0 180us. R1 (256,5) spill+LDS dead end. R2/R3 SWZ swizzle
// (conflicts 6.29M->1.05M) cancelled by spill. R4 GA 455us. R5 r-proj in
// phase3 -> 174.5. R6 [fused prep + W-b128 + setprio] -> 138.9. R7 (256,2)
// 256-reg budget, no spill -> 127.4. R8 (256,3) = identical codegen (HW
// wave slots quantize at 128/256 regs) -> neutral. R9 2-batch fusion:
// +1.6% only -- per-wave ILP is NOT the binding constraint at 2 waves/SIMD;
// wave COUNT is.
// R10: get combined register demand <= 128 so waves fit 128-reg HW slots.
// The last 32-reg persistent item (hoisted fp8 A-fragments) moves to a
// 5th LDS region: e stays resident in LDS all kernel; phase1/r-proj read
// aT[4] (8 regs, tm-transient) per tm-tile. Demand ~140-32 ~= 108 < 128.
// LDS = 5 x 8192 = 40960 B -> 3 blocks/CU = 12 waves/CU (3 waves/SIMD,
// +50% wave supply vs R7/R9). (256,4) forces the <=128 allocation.
// Pass/fail: OccupancyPercent ~33+ and WRITE_SIZE stays ~64 KB.

typedef __attribute__((ext_vector_type(8))) __bf16 bf16x8;
typedef __attribute__((ext_vector_type(4))) float f32x4;
typedef __attribute__((ext_vector_type(2))) long long llx2;

#define LDP 72            // padded row stride (shorts) -- fallback kernel only
#define E_SCALE 64.0f     // e -> fp8 pre-scale
#define W_SCALE 8.0f      // W -> fp8 pre-scale
#define INV_RAW (1.0f / 512.0f)            // undo E_SCALE*W_SCALE
#define INV_RAW2 (1.0f / (512.0f * 512.0f))  // undo (E*W)^2 in scores

// swizzled [64][64] short-index; involution applied on both write and read.
// Measured (R1): bank conflicts 6.29M -> 1.05M vs the LDP=72 pad.
#define SWZ(row, col) (((row) * 64) + ((col) ^ (((row) & 7) << 3)))

// RNE f2bf (prep/fallback only)
__device__ inline unsigned short f2bf(float f) {
    unsigned u = __float_as_uint(f);
    return (unsigned short)((u + 0x7fff + ((u >> 16) & 1)) >> 16);
}
// truncating f2bf for LDS scatters (<=0.39% one-sided rel err on intermediates)
__device__ inline unsigned short f2bf_t(float f) {
    return (unsigned short)(__float_as_uint(f) >> 16);
}
// pack two f32 -> two bf16 in one dword (lo=a, hi=b)
__device__ inline unsigned pack_bf2(float a, float b) {
#if __has_builtin(__builtin_amdgcn_cvt_pk_bf16_f32)
    typedef __attribute__((ext_vector_type(2))) __bf16 bf16x2;
    bf16x2 r = __builtin_amdgcn_cvt_pk_bf16_f32(a, b);
    return *(unsigned*)&r;
#else
    return (__float_as_uint(a) >> 16) | (__float_as_uint(b) & 0xFFFF0000u);
#endif
}
// pack 4 f32 -> 4 fp8 e4m3 bytes in one dword
__device__ inline unsigned pack_fp8x4(float a, float b, float c, float d) {
#if __has_builtin(__builtin_amdgcn_cvt_pk_fp8_f32)
    int u = __builtin_amdgcn_cvt_pk_fp8_f32(a, b, 0, false);
    u = __builtin_amdgcn_cvt_pk_fp8_f32(c, d, u, true);
    return (unsigned)u;
#else
    __hip_fp8_e4m3 qa(a), qb(b), qc(c), qd(d);
    return (unsigned)qa.__x | ((unsigned)qb.__x << 8) |
           ((unsigned)qc.__x << 16) | ((unsigned)qd.__x << 24);
#endif
}

// ---- fused prep ----
// blocks 0..255: transpose+convert W fp32 [128][512] -> fp8 Wt[4][512][...]
//   with PERMUTED inner layout: byte for dim d lands at quad*32 + ks*8 + r
//   (quad=(d>>3)&3, ks=d>>5, r=d&7) -- a lane's 4 MFMA fragments are 32
//   contiguous bytes -> 2 b128 loads.
// blocks 256..383: transpose out_w [32768] -> ow2[h*64+p][f] (128 KB).
__global__ __launch_bounds__(256) void prep_w(
        const float* __restrict__ Wq, const float* __restrict__ Wk,
        const float* __restrict__ Wv, const float* __restrict__ Wr,
        const float* __restrict__ out_w,
        unsigned char* __restrict__ Wt, float* __restrict__ ow2) {
    int blk = blockIdx.x;
    if (blk >= 256) {
        int i = (blk - 256) * 256 + threadIdx.x;   // 0..32767
        int f = i & 63;
        int hp = i >> 6;                           // h*64+p
        ow2[i] = out_w[(size_t)f * 512 + hp];
        return;
    }
    __shared__ float t[64][20];
    int mat = blk >> 6;
    int dt8 = (blk >> 3) & 7;        // 16-row group of d
    int ct  = blk & 7;               // 64-col group
    const float* W = (mat == 0) ? Wq : (mat == 1) ? Wk : (mat == 2) ? Wv : Wr;
    int tid  = threadIdx.x;
    int col  = tid & 63;
    int row0 = tid >> 6;             // 0..3
    for (int i = 0; i < 4; i++) {
        int row = row0 + i * 4;      // 0..15 within d-group
        t[col][row] = W[(size_t)(dt8 * 16 + row) * 512 + ct * 64 + col];
    }
    __syncthreads();
    int wc  = tid & 63;
    int seg = tid >> 6;              // 0..3
    unsigned u = pack_fp8x4(t[wc][seg * 4 + 0] * W_SCALE, t[wc][seg * 4 + 1] * W_SCALE,
                            t[wc][seg * 4 + 2] * W_SCALE, t[wc][seg * 4 + 3] * W_SCALE);
    int d0 = dt8 * 16 + seg * 4;     // first d of this dword (d0..d0+3 share quad/ks)
    int q_ = (d0 >> 3) & 3, k_ = d0 >> 5, r_ = d0 & 7;
    *(unsigned*)&Wt[((size_t)mat * 512 + ct * 64 + wc) * 128 + q_ * 32 + k_ * 8 + r_] = u;
}

__global__ __launch_bounds__(256, 4) void autoint_kernel(
        const int* __restrict__ fidx,
        const float* __restrict__ emb,             // [100000][128]
        const unsigned char* __restrict__ Wt,      // fp8 [4][512][128] permuted, x W_SCALE
        const float* __restrict__ ow2,             // [8][64][64] transposed out_w
        const float* __restrict__ out_b,           // [1]
        float* __restrict__ y) {                   // [2048]
    // 40960 B: q | k | vT | att (4 x 4096 shorts, SWZ'd) + e8 (8192 B fp8,
    // A-fragment order, RESIDENT all kernel -- replaces the 32-VGPR hoist).
    // final red[] overlays att (dead after h=7 phase3 + final barrier).
    __shared__ __align__(16) unsigned short smem[5 * 4096];
    unsigned short* q_lds   = smem;
    unsigned short* k_lds   = smem + 4096;
    unsigned short* vT_lds  = smem + 2 * 4096;
    unsigned short* att_lds = smem + 3 * 4096;
    unsigned char*  e8      = (unsigned char*)(smem + 4 * 4096);

    const int b    = blockIdx.x;
    const int tid  = threadIdx.x;
    const int wave = tid >> 6;
    const int lane = tid & 63;
    const int quad = lane >> 4;
    const int ln16 = lane & 15;

    const int* idx = fidx + b * 64;

    // ---- stage e (fp32 -> fp8 x E_SCALE) in A-fragment order, resident ----
    // slot s: tm=s>>8, ks=(s>>6)&3, quad=(s>>4)&3, m=s&15
    // holds e[f=tm*16+m][d = ks*32 + quad*8 + 0..7], 8 bytes per slot
    for (int it = 0; it < 4; it++) {
        int s  = tid + it * 256;
        int tm = s >> 8, ks = (s >> 6) & 3, qd = (s >> 4) & 3, m = s & 15;
        int f  = tm * 16 + m;
        const float* src = emb + (size_t)idx[f] * 128 + ks * 32 + qd * 8;
        float4 lo = *(const float4*)src;
        float4 hi = *(const float4*)(src + 4);
        uint2 pk;
        pk.x = pack_fp8x4(lo.x * E_SCALE, lo.y * E_SCALE, lo.z * E_SCALE, lo.w * E_SCALE);
        pk.y = pack_fp8x4(hi.x * E_SCALE, hi.y * E_SCALE, hi.z * E_SCALE, hi.w * E_SCALE);
        *(uint2*)&e8[s * 8] = pk;
    }
    __syncthreads();

    float acc_out = 0.f;

    // W fragment loader: lane's 4 fragments for (mat m, head h) are 32
    // contiguous bytes (permuted layout) -> 2 b128 loads.
    auto loadW = [&](int m, int h, long long (&bf)[4]) {
        const unsigned char* WtM =
            Wt + ((size_t)m * 512 + h * 64 + wave * 16 + ln16) * 128 + quad * 32;
        llx2 w01 = *(const llx2*)WtM;
        llx2 w23 = *(const llx2*)(WtM + 16);
        bf[0] = w01[0]; bf[1] = w01[1]; bf[2] = w23[0]; bf[3] = w23[1];
    };
    // A-fragment loader: 4 b64 LDS reads for one tm row-tile (8 regs,
    // transient -- this is what replaced the 32-reg persistent hoist).
    auto loadA = [&](int tm, long long (&aT)[4]) {
        for (int ks = 0; ks < 4; ks++)
            aT[ks] = *(const long long*)&e8[((tm * 4 + ks) * 64 + lane) * 8];
    };

    // phase1: project p-slice [wave*16,+16) of q,k,vT from preloaded W frags.
    // tm-outer / m-inner so aT (8 regs) is reused across all 3 mats.
    auto phase1 = [&](const long long (&bfm)[3][4]) {
        for (int tm = 0; tm < 4; tm++) {
            long long aT[4];
            loadA(tm, aT);
            for (int m = 0; m < 3; m++) {
                f32x4 acc = {0.f, 0.f, 0.f, 0.f};
                __builtin_amdgcn_s_setprio(1);
                for (int ks = 0; ks < 4; ks++)
                    acc = __builtin_amdgcn_mfma_f32_16x16x32_fp8_fp8(aT[ks], bfm[m][ks], acc, 0, 0, 0);
                __builtin_amdgcn_s_setprio(0);
                if (m == 0) {
                    for (int r = 0; r < 4; r++)
                        q_lds[SWZ(tm * 16 + quad * 4 + r, wave * 16 + ln16)] = f2bf_t(acc[r]);
                } else if (m == 1) {
                    for (int r = 0; r < 4; r++)
                        k_lds[SWZ(tm * 16 + quad * 4 + r, wave * 16 + ln16)] = f2bf_t(acc[r]);
                } else {
                    uint2 pk;
                    pk.x = pack_bf2(acc[0], acc[1]);
                    pk.y = pack_bf2(acc[2], acc[3]);
                    // wave-private rows w*16..w*16+15
                    *(uint2*)&vT_lds[SWZ(wave * 16 + ln16, tm * 16 + quad * 4)] = pk;
                }
            }
        }
    };

    {
        long long bfm[3][4];
        for (int m = 0; m < 3; m++) loadW(m, 0, bfm[m]);
        phase1(bfm);
    }
    __syncthreads();

    for (int h = 0; h < 8; h++) {
        // ---- phase2: scores_raw = q_raw @ k_raw^T; softmax over q (columns) ----
        {
            float sc[4][4];
            float sum = 0.f;
            for (int tm = 0; tm < 4; tm++) {
                f32x4 acc = {0.f, 0.f, 0.f, 0.f};
                __builtin_amdgcn_s_setprio(1);
                for (int ks = 0; ks < 2; ks++) {
                    bf16x8 af = *(const bf16x8*)&q_lds[SWZ(tm * 16 + ln16, ks * 32 + quad * 8)];
                    bf16x8 bb = *(const bf16x8*)&k_lds[SWZ(wave * 16 + ln16, ks * 32 + quad * 8)];
                    acc = __builtin_amdgcn_mfma_f32_16x16x32_bf16(af, bb, acc, 0, 0, 0);
                }
                __builtin_amdgcn_s_setprio(0);
                for (int r = 0; r < 4; r++) {
                    float e = __expf(acc[r] * INV_RAW2);
                    sc[tm][r] = e;
                    sum += e;
                }
            }
            sum += __shfl_xor(sum, 16);
            sum += __shfl_xor(sum, 32);
            float inv = 1.f / sum;
            for (int tm = 0; tm < 4; tm++)
                for (int r = 0; r < 4; r++)
                    att_lds[SWZ(tm * 16 + quad * 4 + r, wave * 16 + ln16)] =
                        f2bf_t(sc[tm][r] * inv);
        }
        __syncthreads();

        // ---- merged interval: [all W loads] phase3(h)+r-proj ; phase1(h+1) ----
        // All VMEM issues up-front (8 b128): latency hides under phase3's
        // MFMAs. vT reads precede same-wave vT writes; q,k,att hazards cross
        // the surrounding barriers.
        {
            long long bfr[4];
            loadW(3, h, bfr);
            long long bfn[3][4];
            if (h < 7)
                for (int m = 0; m < 3; m++) loadW(m, h + 1, bfn[m]);
            const float* owr = ow2 + ((size_t)(h * 64 + wave * 16 + ln16)) * 64;
            for (int tm = 0; tm < 4; tm++) {
                float4 owv = *(const float4*)&owr[tm * 16 + quad * 4];
                long long aT[4];
                loadA(tm, aT);
                f32x4 acc = {0.f, 0.f, 0.f, 0.f};
                f32x4 racc = {0.f, 0.f, 0.f, 0.f};
                __builtin_amdgcn_s_setprio(1);
                for (int ks = 0; ks < 2; ks++) {
                    bf16x8 af = *(const bf16x8*)&att_lds[SWZ(tm * 16 + ln16, ks * 32 + quad * 8)];
                    bf16x8 bb = *(const bf16x8*)&vT_lds[SWZ(wave * 16 + ln16, ks * 32 + quad * 8)];
                    acc = __builtin_amdgcn_mfma_f32_16x16x32_bf16(af, bb, acc, 0, 0, 0);
                }
                for (int ks = 0; ks < 4; ks++)
                    racc = __builtin_amdgcn_mfma_f32_16x16x32_fp8_fp8(aT[ks], bfr[ks], racc, 0, 0, 0);
                __builtin_amdgcn_s_setprio(0);
                // branchless relu
                acc_out += fmaxf(acc[0] + racc[0], 0.f) * owv.x;
                acc_out += fmaxf(acc[1] + racc[1], 0.f) * owv.y;
                acc_out += fmaxf(acc[2] + racc[2], 0.f) * owv.z;
                acc_out += fmaxf(acc[3] + racc[3], 0.f) * owv.w;
            }
            if (h < 7) phase1(bfn);
        }
        __syncthreads();
    }

    // ---- block reduction, undo raw scale, sigmoid ----
    // red[] overlays the att region (att dead after h=7 phase3; the loop's
    // final barrier orders all waves' last reads before this write).
    float* red = (float*)att_lds;
    for (int off = 32; off >= 1; off >>= 1) acc_out += __shfl_xor(acc_out, off);
    if (lane == 0) red[wave] = acc_out;
    __syncthreads();
    if (tid == 0) {
        float s = (red[0] + red[1] + red[2] + red[3]) * INV_RAW + out_b[0];
        y[b] = 1.f / (1.f + __expf(-s));
    }
}

// Fallback (no usable workspace): bf16 path, per-head strided W gather.
__global__ __launch_bounds__(256) void autoint_kernel_nows(
        const int* __restrict__ fidx,
        const float* __restrict__ emb,
        const float* __restrict__ W0, const float* __restrict__ W1,
        const float* __restrict__ W2, const float* __restrict__ W3,
        const float* __restrict__ out_w, const float* __restrict__ out_b,
        float* __restrict__ y) {
    __shared__ __align__(16) unsigned short escratch[64 * 128];
    __shared__ __align__(16) unsigned short q_lds[64 * LDP];
    __shared__ __align__(16) unsigned short k_lds[64 * LDP];
    __shared__ __align__(16) unsigned short vT_lds[64 * LDP];
    __shared__ float red[4];

    const int b    = blockIdx.x;
    const int tid  = threadIdx.x;
    const int wave = tid >> 6;
    const int lane = tid & 63;
    const int quad = lane >> 4;
    const int ln16 = lane & 15;
    const int* idx = fidx + b * 64;

    for (int it = 0; it < 4; it++) {
        int s  = tid + it * 256;
        int tm = s >> 8, ks = (s >> 6) & 3, qd = (s >> 4) & 3, m = s & 15;
        int f  = tm * 16 + m;
        const float* src = emb + (size_t)idx[f] * 128 + ks * 32 + qd * 8;
        float4 lo = *(const float4*)src;
        float4 hi = *(const float4*)(src + 4);
        uint4 pk;
        pk.x = pack_bf2(lo.x, lo.y); pk.y = pack_bf2(lo.z, lo.w);
        pk.z = pack_bf2(hi.x, hi.y); pk.w = pack_bf2(hi.z, hi.w);
        *(uint4*)&escratch[s * 8] = pk;
    }
    __syncthreads();

    bf16x8 a[4][4];
    for (int tm = 0; tm < 4; tm++)
        for (int ks = 0; ks < 4; ks++)
            a[tm][ks] = *(const bf16x8*)&escratch[((tm * 4 + ks) * 64 + lane) * 8];
    unsigned short* att_lds = escratch;

    float acc_out = 0.f;
    f32x4 r_reg[4];

    for (int h = 0; h < 8; h++) {
        for (int m = 0; m < 4; m++) {
            const float* Wsel = (m == 0) ? W0 : (m == 1) ? W1 : (m == 2) ? W2 : W3;
            bf16x8 bf[4];
            for (int ks = 0; ks < 4; ks++) {
                union { unsigned short u[8]; bf16x8 v; } p;
                const float* base = Wsel + (size_t)(ks * 32 + quad * 8) * 512
                                    + h * 64 + wave * 16 + ln16;
                for (int j = 0; j < 8; j++) p.u[j] = f2bf(base[(size_t)j * 512]);
                bf[ks] = p.v;
            }
            for (int tm = 0; tm < 4; tm++) {
                f32x4 acc = {0.f, 0.f, 0.f, 0.f};
                for (int ks = 0; ks < 4; ks++)
                    acc = __builtin_amdgcn_mfma_f32_16x16x32_bf16(a[tm][ks], bf[ks], acc, 0, 0, 0);
                if (m == 0) {
                    for (int r = 0; r < 4; r++)
                        q_lds[(tm * 16 + quad * 4 + r) * LDP + wave * 16 + ln16] = f2bf_t(acc[r]);
                } else if (m == 1) {
                    for (int r = 0; r < 4; r++)
                        k_lds[(tm * 16 + quad * 4 + r) * LDP + wave * 16 + ln16] = f2bf_t(acc[r]);
                } else if (m == 2) {
                    uint2 pk;
                    pk.x = pack_bf2(acc[0], acc[1]);
                    pk.y = pack_bf2(acc[2], acc[3]);
                    *(uint2*)&vT_lds[(wave * 16 + ln16) * LDP + tm * 16 + quad * 4] = pk;
                } else {
                    r_reg[tm] = acc;
                }
            }
        }
        __syncthreads();
        {
            float sc[4][4];
            float sum = 0.f;
            for (int tm = 0; tm < 4; tm++) {
                f32x4 acc = {0.f, 0.f, 0.f, 0.f};
                for (int ks = 0; ks < 2; ks++) {
                    bf16x8 af = *(const bf16x8*)&q_lds[(tm * 16 + ln16) * LDP + ks * 32 + quad * 8];
                    bf16x8 bb = *(const bf16x8*)&k_lds[(wave * 16 + ln16) * LDP + ks * 32 + quad * 8];
                    acc = __builtin_amdgcn_mfma_f32_16x16x32_bf16(af, bb, acc, 0, 0, 0);
                }
                for (int r = 0; r < 4; r++) {
                    float e = __expf(acc[r]);
                    sc[tm][r] = e;
                    sum += e;
                }
            }
            sum += __shfl_xor(sum, 16);
            sum += __shfl_xor(sum, 32);
            float inv = 1.f / sum;
            for (int tm = 0; tm < 4; tm++)
                for (int r = 0; r < 4; r++)
                    att_lds[(tm * 16 + quad * 4 + r) * LDP + wave * 16 + ln16] =
                        f2bf_t(sc[tm][r] * inv);
        }
        __syncthreads();
        {
            const float* ow = out_w + h * 64 + wave * 16;
            for (int tm = 0; tm < 4; tm++) {
                f32x4 acc = {0.f, 0.f, 0.f, 0.f};
                for (int ks = 0; ks < 2; ks++) {
                    bf16x8 af = *(const bf16x8*)&att_lds[(tm * 16 + ln16) * LDP + ks * 32 + quad * 8];
                    bf16x8 bb = *(const bf16x8*)&vT_lds[(wave * 16 + ln16) * LDP + ks * 32 + quad * 8];
                    acc = __builtin_amdgcn_mfma_f32_16x16x32_bf16(af, bb, acc, 0, 0, 0);
                }
                for (int r = 0; r < 4; r++) {
                    int f = tm * 16 + quad * 4 + r;
                    float mval = acc[r] + r_reg[tm][r];
                    if (mval > 0.f) acc_out += mval * ow[(size_t)f * 512 + ln16];
                }
            }
        }
        __syncthreads();
    }
    for (int off = 32; off >= 1; off >>= 1) acc_out += __shfl_xor(acc_out, off);
    if (lane == 0) red[wave] = acc_out;
    __syncthreads();
    if (tid == 0) {
        float s = red[0] + red[1] + red[2] + red[3] + out_b[0];
        y[b] = 1.f / (1.f + __expf(-s));
    }
}

extern "C" void kernel_launch(void* const* d_in, const int* in_sizes, int n_in,
                              void* d_out, int out_size, void* d_ws, size_t ws_size,
                              hipStream_t stream) {
    (void)in_sizes; (void)n_in; (void)out_size;
    const int*   fidx = (const int*)d_in[0];
    const float* emb  = (const float*)d_in[1];
    const float* Wq   = (const float*)d_in[2];
    const float* Wk   = (const float*)d_in[3];
    const float* Wv   = (const float*)d_in[4];
    const float* Wr   = (const float*)d_in[5];
    const float* ow   = (const float*)d_in[6];
    const float* ob   = (const float*)d_in[7];
    float*       yy   = (float*)d_out;

    const size_t wt_bytes  = (size_t)4 * 512 * 128;   // 256 KB (fp8 W, permuted)
    const size_t ow2_bytes = (size_t)8 * 64 * 64 * 4; // 128 KB (transposed out_w)
    if (d_ws != nullptr && ws_size >= wt_bytes + ow2_bytes) {
        unsigned char* Wt  = (unsigned char*)d_ws;
        float*         ow2 = (float*)((unsigned char*)d_ws + wt_bytes);
        prep_w<<<384, 256, 0, stream>>>(Wq, Wk, Wv, Wr, ow, Wt, ow2);
        autoint_kernel<<<2048, 256, 0, stream>>>(fidx, emb, Wt, ow2, ob, yy);
    } else {
        autoint_kernel_nows<<<2048, 256, 0, stream>>>(fidx, emb, Wq, Wk, Wv, Wr, ow, ob, yy);
    }
}

// Round 11
// 187.602 us; speedup vs baseline: 1.1155x; 1.1155x over previous
//
#include <hip/hip_runtime.h>
#include <hip/hip_bf16.h>
#include <hip/hip_fp8.h>
#include <stdint.h>

// AutoInt: B=2048, F=64, D=128, H=8, P=64, V=100000 -- FP32 in/out.
// R11 = R9 base (2 batches/block, grid 1024, 4 waves, (256,2)) with the two
// batches' chains interleaved at INSTRUCTION granularity: phase1_both pairs
// mfma(a[0],W) with mfma(a[1],W) (shared B operand), phase2_both alternates
// the batches' LDS loads/MFMAs/exp chains. R9 called phase1/phase2 per batch
// sequentially -- independent chains sat too far apart for the scheduler;
// phase3 (already j-inside-tm) was the only interleaved phase.
//
// Ledger: R0 180us. R1 (256,5) spill+LDS dead end. R2/R3 SWZ (conflicts
// 6.29M->1.05M) cancelled by spill. R4 GA 455us. R5 r-proj in phase3 ->
// 174.5. R6 [fused prep + W-b128 + setprio] -> 138.9. R7 (256,2) no spill
// -> 127.4. R8 (256,3): HW wave slots quantize at 128/256 regs -> neutral.
// R9 2-batch coarse fusion -> 125.5 (+1.6% only). R10 LDS-resident A-frags
// -> 3 blocks/CU, 39% occupancy, but 133.5us REGRESSION: more waves lose
// to the added LDS traffic. Binding constraint = per-wave dependent-chain
// latency; this round pairs each stall with an adjacent independent op.

typedef __attribute__((ext_vector_type(8))) __bf16 bf16x8;
typedef __attribute__((ext_vector_type(4))) float f32x4;
typedef __attribute__((ext_vector_type(2))) long long llx2;

#define LDP 72            // padded row stride (shorts) -- fallback kernel only
#define E_SCALE 64.0f     // e -> fp8 pre-scale
#define W_SCALE 8.0f      // W -> fp8 pre-scale
#define INV_RAW (1.0f / 512.0f)            // undo E_SCALE*W_SCALE
#define INV_RAW2 (1.0f / (512.0f * 512.0f))  // undo (E*W)^2 in scores

// swizzled [64][64] short-index; involution applied on both write and read.
// Measured (R1): bank conflicts 6.29M -> 1.05M vs the LDP=72 pad.
#define SWZ(row, col) (((row) * 64) + ((col) ^ (((row) & 7) << 3)))

// per-batch LDS regions (shorts): batch j owns 16384 shorts (32 KB)
#define QL(j)  (smem + (j) * 16384)
#define KL(j)  (smem + (j) * 16384 + 4096)
#define VTL(j) (smem + (j) * 16384 + 8192)
#define ATL(j) (smem + (j) * 16384 + 12288)

// RNE f2bf (prep/fallback only)
__device__ inline unsigned short f2bf(float f) {
    unsigned u = __float_as_uint(f);
    return (unsigned short)((u + 0x7fff + ((u >> 16) & 1)) >> 16);
}
// truncating f2bf for LDS scatters (<=0.39% one-sided rel err on intermediates)
__device__ inline unsigned short f2bf_t(float f) {
    return (unsigned short)(__float_as_uint(f) >> 16);
}
// pack two f32 -> two bf16 in one dword (lo=a, hi=b)
__device__ inline unsigned pack_bf2(float a, float b) {
#if __has_builtin(__builtin_amdgcn_cvt_pk_bf16_f32)
    typedef __attribute__((ext_vector_type(2))) __bf16 bf16x2;
    bf16x2 r = __builtin_amdgcn_cvt_pk_bf16_f32(a, b);
    return *(unsigned*)&r;
#else
    return (__float_as_uint(a) >> 16) | (__float_as_uint(b) & 0xFFFF0000u);
#endif
}
// pack 4 f32 -> 4 fp8 e4m3 bytes in one dword
__device__ inline unsigned pack_fp8x4(float a, float b, float c, float d) {
#if __has_builtin(__builtin_amdgcn_cvt_pk_fp8_f32)
    int u = __builtin_amdgcn_cvt_pk_fp8_f32(a, b, 0, false);
    u = __builtin_amdgcn_cvt_pk_fp8_f32(c, d, u, true);
    return (unsigned)u;
#else
    __hip_fp8_e4m3 qa(a), qb(b), qc(c), qd(d);
    return (unsigned)qa.__x | ((unsigned)qb.__x << 8) |
           ((unsigned)qc.__x << 16) | ((unsigned)qd.__x << 24);
#endif
}

// ---- fused prep ----
// blocks 0..255: transpose+convert W fp32 [128][512] -> fp8 Wt[4][512][...]
//   with PERMUTED inner layout: byte for dim d lands at quad*32 + ks*8 + r
//   (quad=(d>>3)&3, ks=d>>5, r=d&7) -- a lane's 4 MFMA fragments are 32
//   contiguous bytes -> 2 b128 loads.
// blocks 256..383: transpose out_w [32768] -> ow2[h*64+p][f] (128 KB).
__global__ __launch_bounds__(256) void prep_w(
        const float* __restrict__ Wq, const float* __restrict__ Wk,
        const float* __restrict__ Wv, const float* __restrict__ Wr,
        const float* __restrict__ out_w,
        unsigned char* __restrict__ Wt, float* __restrict__ ow2) {
    int blk = blockIdx.x;
    if (blk >= 256) {
        int i = (blk - 256) * 256 + threadIdx.x;   // 0..32767
        int f = i & 63;
        int hp = i >> 6;                           // h*64+p
        ow2[i] = out_w[(size_t)f * 512 + hp];
        return;
    }
    __shared__ float t[64][20];
    int mat = blk >> 6;
    int dt8 = (blk >> 3) & 7;        // 16-row group of d
    int ct  = blk & 7;               // 64-col group
    const float* W = (mat == 0) ? Wq : (mat == 1) ? Wk : (mat == 2) ? Wv : Wr;
    int tid  = threadIdx.x;
    int col  = tid & 63;
    int row0 = tid >> 6;             // 0..3
    for (int i = 0; i < 4; i++) {
        int row = row0 + i * 4;      // 0..15 within d-group
        t[col][row] = W[(size_t)(dt8 * 16 + row) * 512 + ct * 64 + col];
    }
    __syncthreads();
    int wc  = tid & 63;
    int seg = tid >> 6;              // 0..3
    unsigned u = pack_fp8x4(t[wc][seg * 4 + 0] * W_SCALE, t[wc][seg * 4 + 1] * W_SCALE,
                            t[wc][seg * 4 + 2] * W_SCALE, t[wc][seg * 4 + 3] * W_SCALE);
    int d0 = dt8 * 16 + seg * 4;     // first d of this dword (d0..d0+3 share quad/ks)
    int q_ = (d0 >> 3) & 3, k_ = d0 >> 5, r_ = d0 & 7;
    *(unsigned*)&Wt[((size_t)mat * 512 + ct * 64 + wc) * 128 + q_ * 32 + k_ * 8 + r_] = u;
}

__global__ __launch_bounds__(256, 2) void autoint_kernel(
        const int* __restrict__ fidx,
        const float* __restrict__ emb,             // [100000][128]
        const unsigned char* __restrict__ Wt,      // fp8 [4][512][128] permuted, x W_SCALE
        const float* __restrict__ ow2,             // [8][64][64] transposed out_w
        const float* __restrict__ out_b,           // [1]
        float* __restrict__ y) {                   // [2048]
    // 64 KB: two 32-KB batch regions, each q|k|vT|att (4 x 4096 shorts).
    // Batch j's fp8 e staging (8 KB) overlays its q region in the prologue;
    // final red[] overlays q0 after the last phase2.
    __shared__ __align__(16) unsigned short smem[8 * 4096];
    unsigned char* smem8 = (unsigned char*)smem;

    const int b2   = blockIdx.x;          // handles batches 2*b2, 2*b2+1
    const int tid  = threadIdx.x;
    const int wave = tid >> 6;
    const int lane = tid & 63;
    const int quad = lane >> 4;
    const int ln16 = lane & 15;

    const int* idx0 = fidx + (size_t)(2 * b2) * 64;
    const int* idx1 = idx0 + 64;

    // ---- stage e for BOTH batches (fp32 -> fp8 x E_SCALE), A-frag order ----
    for (int it = 0; it < 8; it++) {
        int s  = tid + it * 256;          // 0..2047
        int j  = s >> 10;
        int ss = s & 1023;
        int tm = ss >> 8, ks = (ss >> 6) & 3, qd = (ss >> 4) & 3, m = ss & 15;
        int f  = tm * 16 + m;
        const int* idx = j ? idx1 : idx0;
        const float* src = emb + (size_t)idx[f] * 128 + ks * 32 + qd * 8;
        float4 lo = *(const float4*)src;
        float4 hi = *(const float4*)(src + 4);
        uint2 pk;
        pk.x = pack_fp8x4(lo.x * E_SCALE, lo.y * E_SCALE, lo.z * E_SCALE, lo.w * E_SCALE);
        pk.y = pack_fp8x4(hi.x * E_SCALE, hi.y * E_SCALE, hi.z * E_SCALE, hi.w * E_SCALE);
        *(uint2*)&smem8[j * 32768 + ss * 8] = pk;   // overlays batch j's q region
    }
    __syncthreads();

    // ---- hoist fp8 e A-fragments (both batches, 64 VGPRs) ----
    long long a[2][4][4];
#pragma unroll
    for (int j = 0; j < 2; j++)
        for (int tm = 0; tm < 4; tm++)
            for (int ks = 0; ks < 4; ks++)
                a[j][tm][ks] =
                    *(const long long*)&smem8[j * 32768 + ((tm * 4 + ks) * 64 + lane) * 8];
    __syncthreads();   // all A-reads done before phase1 overwrites q regions

    float acc_out[2] = {0.f, 0.f};

    // W fragment loader (SHARED by both batches): lane's 4 fragments for
    // (mat m, head h) are 32 contiguous bytes -> 2 b128 loads.
    auto loadW = [&](int m, int h, long long (&bf)[4]) {
        const unsigned char* WtM =
            Wt + ((size_t)m * 512 + h * 64 + wave * 16 + ln16) * 128 + quad * 32;
        llx2 w01 = *(const llx2*)WtM;
        llx2 w23 = *(const llx2*)(WtM + 16);
        bf[0] = w01[0]; bf[1] = w01[1]; bf[2] = w23[0]; bf[3] = w23[1];
    };

    // phase1_both: project p-slice [wave*16,+16) of q,k,vT for BOTH batches,
    // interleaved at the ks level: each dependent-chain step of batch 0 has
    // batch 1's independent MFMA adjacent (shared B operand bfm[m][ks]).
    auto phase1_both = [&](const long long (&bfm)[3][4]) {
        for (int m = 0; m < 3; m++) {
            for (int tm = 0; tm < 4; tm++) {
                f32x4 acc0 = {0.f, 0.f, 0.f, 0.f};
                f32x4 acc1 = {0.f, 0.f, 0.f, 0.f};
                __builtin_amdgcn_s_setprio(1);
                for (int ks = 0; ks < 4; ks++) {
                    acc0 = __builtin_amdgcn_mfma_f32_16x16x32_fp8_fp8(a[0][tm][ks], bfm[m][ks], acc0, 0, 0, 0);
                    acc1 = __builtin_amdgcn_mfma_f32_16x16x32_fp8_fp8(a[1][tm][ks], bfm[m][ks], acc1, 0, 0, 0);
                }
                __builtin_amdgcn_s_setprio(0);
                if (m == 0) {
                    for (int r = 0; r < 4; r++) {
                        QL(0)[SWZ(tm * 16 + quad * 4 + r, wave * 16 + ln16)] = f2bf_t(acc0[r]);
                        QL(1)[SWZ(tm * 16 + quad * 4 + r, wave * 16 + ln16)] = f2bf_t(acc1[r]);
                    }
                } else if (m == 1) {
                    for (int r = 0; r < 4; r++) {
                        KL(0)[SWZ(tm * 16 + quad * 4 + r, wave * 16 + ln16)] = f2bf_t(acc0[r]);
                        KL(1)[SWZ(tm * 16 + quad * 4 + r, wave * 16 + ln16)] = f2bf_t(acc1[r]);
                    }
                } else {
                    uint2 pk0, pk1;
                    pk0.x = pack_bf2(acc0[0], acc0[1]);
                    pk0.y = pack_bf2(acc0[2], acc0[3]);
                    pk1.x = pack_bf2(acc1[0], acc1[1]);
                    pk1.y = pack_bf2(acc1[2], acc1[3]);
                    // wave-private rows w*16..w*16+15
                    *(uint2*)&VTL(0)[SWZ(wave * 16 + ln16, tm * 16 + quad * 4)] = pk0;
                    *(uint2*)&VTL(1)[SWZ(wave * 16 + ln16, tm * 16 + quad * 4)] = pk1;
                }
            }
        }
    };

    // phase2_both: scores+softmax for BOTH batches, interleaved per tm so
    // batch 1's LDS loads/MFMAs overlap batch 0's exp chain and vice versa.
    auto phase2_both = [&]() {
        float sc0[4][4], sc1[4][4];
        float sum0 = 0.f, sum1 = 0.f;
        for (int tm = 0; tm < 4; tm++) {
            f32x4 acc0 = {0.f, 0.f, 0.f, 0.f};
            f32x4 acc1 = {0.f, 0.f, 0.f, 0.f};
            __builtin_amdgcn_s_setprio(1);
            for (int ks = 0; ks < 2; ks++) {
                bf16x8 af0 = *(const bf16x8*)&QL(0)[SWZ(tm * 16 + ln16, ks * 32 + quad * 8)];
                bf16x8 bb0 = *(const bf16x8*)&KL(0)[SWZ(wave * 16 + ln16, ks * 32 + quad * 8)];
                bf16x8 af1 = *(const bf16x8*)&QL(1)[SWZ(tm * 16 + ln16, ks * 32 + quad * 8)];
                bf16x8 bb1 = *(const bf16x8*)&KL(1)[SWZ(wave * 16 + ln16, ks * 32 + quad * 8)];
                acc0 = __builtin_amdgcn_mfma_f32_16x16x32_bf16(af0, bb0, acc0, 0, 0, 0);
                acc1 = __builtin_amdgcn_mfma_f32_16x16x32_bf16(af1, bb1, acc1, 0, 0, 0);
            }
            __builtin_amdgcn_s_setprio(0);
            for (int r = 0; r < 4; r++) {
                float e0 = __expf(acc0[r] * INV_RAW2);
                float e1 = __expf(acc1[r] * INV_RAW2);
                sc0[tm][r] = e0; sum0 += e0;
                sc1[tm][r] = e1; sum1 += e1;
            }
        }
        // column (q-axis) reductions across quads, both batches
        sum0 += __shfl_xor(sum0, 16);
        sum1 += __shfl_xor(sum1, 16);
        sum0 += __shfl_xor(sum0, 32);
        sum1 += __shfl_xor(sum1, 32);
        float inv0 = 1.f / sum0;
        float inv1 = 1.f / sum1;
        for (int tm = 0; tm < 4; tm++)
            for (int r = 0; r < 4; r++) {
                ATL(0)[SWZ(tm * 16 + quad * 4 + r, wave * 16 + ln16)] =
                    f2bf_t(sc0[tm][r] * inv0);
                ATL(1)[SWZ(tm * 16 + quad * 4 + r, wave * 16 + ln16)] =
                    f2bf_t(sc1[tm][r] * inv1);
            }
    };

    {
        long long bfm[3][4];
        for (int m = 0; m < 3; m++) loadW(m, 0, bfm[m]);
        phase1_both(bfm);
    }
    __syncthreads();

    for (int h = 0; h < 8; h++) {
        phase2_both();
        __syncthreads();

        // ---- merged interval: [shared W loads] phase3(h)+r-proj x2 (already
        //      j-interleaved) ; phase1_both(h+1). vT reads precede same-wave
        //      vT writes; q,k,att hazards cross the surrounding barriers. ----
        {
            long long bfr[4];
            loadW(3, h, bfr);
            long long bfn[3][4];
            if (h < 7)
                for (int m = 0; m < 3; m++) loadW(m, h + 1, bfn[m]);
            const float* owr = ow2 + ((size_t)(h * 64 + wave * 16 + ln16)) * 64;
            for (int tm = 0; tm < 4; tm++) {
                float4 owv = *(const float4*)&owr[tm * 16 + quad * 4];
#pragma unroll
                for (int j = 0; j < 2; j++) {
                    const unsigned short* att_lds = ATL(j);
                    const unsigned short* vT_lds  = VTL(j);
                    f32x4 acc = {0.f, 0.f, 0.f, 0.f};
                    f32x4 racc = {0.f, 0.f, 0.f, 0.f};
                    __builtin_amdgcn_s_setprio(1);
                    for (int ks = 0; ks < 2; ks++) {
                        bf16x8 af = *(const bf16x8*)&att_lds[SWZ(tm * 16 + ln16, ks * 32 + quad * 8)];
                        bf16x8 bb = *(const bf16x8*)&vT_lds[SWZ(wave * 16 + ln16, ks * 32 + quad * 8)];
                        acc = __builtin_amdgcn_mfma_f32_16x16x32_bf16(af, bb, acc, 0, 0, 0);
                    }
                    for (int ks = 0; ks < 4; ks++)
                        racc = __builtin_amdgcn_mfma_f32_16x16x32_fp8_fp8(a[j][tm][ks], bfr[ks], racc, 0, 0, 0);
                    __builtin_amdgcn_s_setprio(0);
                    // branchless relu
                    acc_out[j] += fmaxf(acc[0] + racc[0], 0.f) * owv.x;
                    acc_out[j] += fmaxf(acc[1] + racc[1], 0.f) * owv.y;
                    acc_out[j] += fmaxf(acc[2] + racc[2], 0.f) * owv.z;
                    acc_out[j] += fmaxf(acc[3] + racc[3], 0.f) * owv.w;
                }
            }
            if (h < 7) phase1_both(bfn);
        }
        __syncthreads();
    }

    // ---- block reduction (per batch), undo raw scale, sigmoid ----
    // red[] overlays q0 (dead after h=7 phase2; final loop barrier orders).
    float* red = (float*)QL(0);
#pragma unroll
    for (int j = 0; j < 2; j++) {
        float v = acc_out[j];
        for (int off = 32; off >= 1; off >>= 1) v += __shfl_xor(v, off);
        if (lane == 0) red[j * 4 + wave] = v;
    }
    __syncthreads();
    if (tid < 2) {
        int j = tid;
        float s = (red[j * 4 + 0] + red[j * 4 + 1] + red[j * 4 + 2] + red[j * 4 + 3])
                      * INV_RAW + out_b[0];
        y[2 * b2 + j] = 1.f / (1.f + __expf(-s));
    }
}

// Fallback (no usable workspace): bf16 path, per-head strided W gather.
__global__ __launch_bounds__(256) void autoint_kernel_nows(
        const int* __restrict__ fidx,
        const float* __restrict__ emb,
        const float* __restrict__ W0, const float* __restrict__ W1,
        const float* __restrict__ W2, const float* __restrict__ W3,
        const float* __restrict__ out_w, const float* __restrict__ out_b,
        float* __restrict__ y) {
    __shared__ __align__(16) unsigned short escratch[64 * 128];
    __shared__ __align__(16) unsigned short q_lds[64 * LDP];
    __shared__ __align__(16) unsigned short k_lds[64 * LDP];
    __shared__ __align__(16) unsigned short vT_lds[64 * LDP];
    __shared__ float red[4];

    const int b    = blockIdx.x;
    const int tid  = threadIdx.x;
    const int wave = tid >> 6;
    const int lane = tid & 63;
    const int quad = lane >> 4;
    const int ln16 = lane & 15;
    const int* idx = fidx + b * 64;

    for (int it = 0; it < 4; it++) {
        int s  = tid + it * 256;
        int tm = s >> 8, ks = (s >> 6) & 3, qd = (s >> 4) & 3, m = s & 15;
        int f  = tm * 16 + m;
        const float* src = emb + (size_t)idx[f] * 128 + ks * 32 + qd * 8;
        float4 lo = *(const float4*)src;
        float4 hi = *(const float4*)(src + 4);
        uint4 pk;
        pk.x = pack_bf2(lo.x, lo.y); pk.y = pack_bf2(lo.z, lo.w);
        pk.z = pack_bf2(hi.x, hi.y); pk.w = pack_bf2(hi.z, hi.w);
        *(uint4*)&escratch[s * 8] = pk;
    }
    __syncthreads();

    bf16x8 a[4][4];
    for (int tm = 0; tm < 4; tm++)
        for (int ks = 0; ks < 4; ks++)
            a[tm][ks] = *(const bf16x8*)&escratch[((tm * 4 + ks) * 64 + lane) * 8];
    unsigned short* att_lds = escratch;

    float acc_out = 0.f;
    f32x4 r_reg[4];

    for (int h = 0; h < 8; h++) {
        for (int m = 0; m < 4; m++) {
            const float* Wsel = (m == 0) ? W0 : (m == 1) ? W1 : (m == 2) ? W2 : W3;
            bf16x8 bf[4];
            for (int ks = 0; ks < 4; ks++) {
                union { unsigned short u[8]; bf16x8 v; } p;
                const float* base = Wsel + (size_t)(ks * 32 + quad * 8) * 512
                                    + h * 64 + wave * 16 + ln16;
                for (int j = 0; j < 8; j++) p.u[j] = f2bf(base[(size_t)j * 512]);
                bf[ks] = p.v;
            }
            for (int tm = 0; tm < 4; tm++) {
                f32x4 acc = {0.f, 0.f, 0.f, 0.f};
                for (int ks = 0; ks < 4; ks++)
                    acc = __builtin_amdgcn_mfma_f32_16x16x32_bf16(a[tm][ks], bf[ks], acc, 0, 0, 0);
                if (m == 0) {
                    for (int r = 0; r < 4; r++)
                        q_lds[(tm * 16 + quad * 4 + r) * LDP + wave * 16 + ln16] = f2bf_t(acc[r]);
                } else if (m == 1) {
                    for (int r = 0; r < 4; r++)
                        k_lds[(tm * 16 + quad * 4 + r) * LDP + wave * 16 + ln16] = f2bf_t(acc[r]);
                } else if (m == 2) {
                    uint2 pk;
                    pk.x = pack_bf2(acc[0], acc[1]);
                    pk.y = pack_bf2(acc[2], acc[3]);
                    *(uint2*)&vT_lds[(wave * 16 + ln16) * LDP + tm * 16 + quad * 4] = pk;
                } else {
                    r_reg[tm] = acc;
                }
            }
        }
        __syncthreads();
        {
            float sc[4][4];
            float sum = 0.f;
            for (int tm = 0; tm < 4; tm++) {
                f32x4 acc = {0.f, 0.f, 0.f, 0.f};
                for (int ks = 0; ks < 2; ks++) {
                    bf16x8 af = *(const bf16x8*)&q_lds[(tm * 16 + ln16) * LDP + ks * 32 + quad * 8];
                    bf16x8 bb = *(const bf16x8*)&k_lds[(wave * 16 + ln16) * LDP + ks * 32 + quad * 8];
                    acc = __builtin_amdgcn_mfma_f32_16x16x32_bf16(af, bb, acc, 0, 0, 0);
                }
                for (int r = 0; r < 4; r++) {
                    float e = __expf(acc[r]);
                    sc[tm][r] = e;
                    sum += e;
                }
            }
            sum += __shfl_xor(sum, 16);
            sum += __shfl_xor(sum, 32);
            float inv = 1.f / sum;
            for (int tm = 0; tm < 4; tm++)
                for (int r = 0; r < 4; r++)
                    att_lds[(tm * 16 + quad * 4 + r) * LDP + wave * 16 + ln16] =
                        f2bf_t(sc[tm][r] * inv);
        }
        __syncthreads();
        {
            const float* ow = out_w + h * 64 + wave * 16;
            for (int tm = 0; tm < 4; tm++) {
                f32x4 acc = {0.f, 0.f, 0.f, 0.f};
                for (int ks = 0; ks < 2; ks++) {
                    bf16x8 af = *(const bf16x8*)&att_lds[(tm * 16 + ln16) * LDP + ks * 32 + quad * 8];
                    bf16x8 bb = *(const bf16x8*)&vT_lds[(wave * 16 + ln16) * LDP + ks * 32 + quad * 8];
                    acc = __builtin_amdgcn_mfma_f32_16x16x32_bf16(af, bb, acc, 0, 0, 0);
                }
                for (int r = 0; r < 4; r++) {
                    int f = tm * 16 + quad * 4 + r;
                    float mval = acc[r] + r_reg[tm][r];
                    if (mval > 0.f) acc_out += mval * ow[(size_t)f * 512 + ln16];
                }
            }
        }
        __syncthreads();
    }
    for (int off = 32; off >= 1; off >>= 1) acc_out += __shfl_xor(acc_out, off);
    if (lane == 0) red[wave] = acc_out;
    __syncthreads();
    if (tid == 0) {
        float s = red[0] + red[1] + red[2] + red[3] + out_b[0];
        y[b] = 1.f / (1.f + __expf(-s));
    }
}

extern "C" void kernel_launch(void* const* d_in, const int* in_sizes, int n_in,
                              void* d_out, int out_size, void* d_ws, size_t ws_size,
                              hipStream_t stream) {
    (void)in_sizes; (void)n_in; (void)out_size;
    const int*   fidx = (const int*)d_in[0];
    const float* emb  = (const float*)d_in[1];
    const float* Wq   = (const float*)d_in[2];
    const float* Wk   = (const float*)d_in[3];
    const float* Wv   = (const float*)d_in[4];
    const float* Wr   = (const float*)d_in[5];
    const float* ow   = (const float*)d_in[6];
    const float* ob   = (const float*)d_in[7];
    float*       yy   = (float*)d_out;

    const size_t wt_bytes  = (size_t)4 * 512 * 128;   // 256 KB (fp8 W, permuted)
    const size_t ow2_bytes = (size_t)8 * 64 * 64 * 4; // 128 KB (transposed out_w)
    if (d_ws != nullptr && ws_size >= wt_bytes + ow2_bytes) {
        unsigned char* Wt  = (unsigned char*)d_ws;
        float*         ow2 = (float*)((unsigned char*)d_ws + wt_bytes);
        prep_w<<<384, 256, 0, stream>>>(Wq, Wk, Wv, Wr, ow, Wt, ow2);
        autoint_kernel<<<1024, 256, 0, stream>>>(fidx, emb, Wt, ow2, ob, yy);
    } else {
        autoint_kernel_nows<<<2048, 256, 0, stream>>>(fidx, emb, Wq, Wk, Wv, Wr, ow, ob, yy);
    }
}

// Round 12
// 187.235 us; speedup vs baseline: 1.1177x; 1.0020x over previous
//
#include <hip/hip_runtime.h>
#include <hip/hip_bf16.h>
#include <hip/hip_fp8.h>
#include <stdint.h>

// AutoInt: B=2048, F=64, D=128, H=8, P=64, V=100000 -- FP32 in/out.
// R12 = R11 (2 batches/block, instruction-interleaved) with chain-width
// widened 2 -> 4: MFMA dependent latency (~16-20cy vs ~5cy issue) needs ~4
// independent chains. phase1/phase2 pair tm-tiles (j x t chains share the W
// fragment); phase3 hoists the setprio bracket out of the j loop and
// explicitly interleaves acc0/acc1 + racc0/racc1.
//
// Ledger: R0 180us. R1 (256,5) spill+LDS dead end. R2/R3 SWZ (conflicts
// 6.29M->1.05M) cancelled by spill. R4 GA 455us. R5 r-proj in phase3 ->
// 174.5. R6 [fused prep + W-b128 + setprio] -> 138.9. R7 (256,2) no spill
// -> 127.4. R8 (256,3): HW wave slots quantize at 128/256 regs -> neutral.
// R9 coarse 2-batch fusion -> 125.5 (+1.6%: whole-phase sequencing too far
// apart for the scheduler). R10 LDS-resident A-frags: 3 blk/CU, 39% occ,
// but 133.5 REGRESSION (more waves lose to added LDS traffic). R11
// instruction-granular 2-chain interleave -> 109.8 (-12.5%), MfmaUtil 32.
// Binding constraint: per-wave dependent-chain latency. This round: 4 chains.

typedef __attribute__((ext_vector_type(8))) __bf16 bf16x8;
typedef __attribute__((ext_vector_type(4))) float f32x4;
typedef __attribute__((ext_vector_type(2))) long long llx2;

#define LDP 72            // padded row stride (shorts) -- fallback kernel only
#define E_SCALE 64.0f     // e -> fp8 pre-scale
#define W_SCALE 8.0f      // W -> fp8 pre-scale
#define INV_RAW (1.0f / 512.0f)            // undo E_SCALE*W_SCALE
#define INV_RAW2 (1.0f / (512.0f * 512.0f))  // undo (E*W)^2 in scores

// swizzled [64][64] short-index; involution applied on both write and read.
// Measured (R1): bank conflicts 6.29M -> 1.05M vs the LDP=72 pad.
#define SWZ(row, col) (((row) * 64) + ((col) ^ (((row) & 7) << 3)))

// per-batch LDS regions (shorts): batch j owns 16384 shorts (32 KB)
#define QL(j)  (smem + (j) * 16384)
#define KL(j)  (smem + (j) * 16384 + 4096)
#define VTL(j) (smem + (j) * 16384 + 8192)
#define ATL(j) (smem + (j) * 16384 + 12288)

// RNE f2bf (prep/fallback only)
__device__ inline unsigned short f2bf(float f) {
    unsigned u = __float_as_uint(f);
    return (unsigned short)((u + 0x7fff + ((u >> 16) & 1)) >> 16);
}
// truncating f2bf for LDS scatters (<=0.39% one-sided rel err on intermediates)
__device__ inline unsigned short f2bf_t(float f) {
    return (unsigned short)(__float_as_uint(f) >> 16);
}
// pack two f32 -> two bf16 in one dword (lo=a, hi=b)
__device__ inline unsigned pack_bf2(float a, float b) {
#if __has_builtin(__builtin_amdgcn_cvt_pk_bf16_f32)
    typedef __attribute__((ext_vector_type(2))) __bf16 bf16x2;
    bf16x2 r = __builtin_amdgcn_cvt_pk_bf16_f32(a, b);
    return *(unsigned*)&r;
#else
    return (__float_as_uint(a) >> 16) | (__float_as_uint(b) & 0xFFFF0000u);
#endif
}
// pack 4 f32 -> 4 fp8 e4m3 bytes in one dword
__device__ inline unsigned pack_fp8x4(float a, float b, float c, float d) {
#if __has_builtin(__builtin_amdgcn_cvt_pk_fp8_f32)
    int u = __builtin_amdgcn_cvt_pk_fp8_f32(a, b, 0, false);
    u = __builtin_amdgcn_cvt_pk_fp8_f32(c, d, u, true);
    return (unsigned)u;
#else
    __hip_fp8_e4m3 qa(a), qb(b), qc(c), qd(d);
    return (unsigned)qa.__x | ((unsigned)qb.__x << 8) |
           ((unsigned)qc.__x << 16) | ((unsigned)qd.__x << 24);
#endif
}

// ---- fused prep ----
// blocks 0..255: transpose+convert W fp32 [128][512] -> fp8 Wt[4][512][...]
//   with PERMUTED inner layout: byte for dim d lands at quad*32 + ks*8 + r
//   (quad=(d>>3)&3, ks=d>>5, r=d&7) -- a lane's 4 MFMA fragments are 32
//   contiguous bytes -> 2 b128 loads.
// blocks 256..383: transpose out_w [32768] -> ow2[h*64+p][f] (128 KB).
__global__ __launch_bounds__(256) void prep_w(
        const float* __restrict__ Wq, const float* __restrict__ Wk,
        const float* __restrict__ Wv, const float* __restrict__ Wr,
        const float* __restrict__ out_w,
        unsigned char* __restrict__ Wt, float* __restrict__ ow2) {
    int blk = blockIdx.x;
    if (blk >= 256) {
        int i = (blk - 256) * 256 + threadIdx.x;   // 0..32767
        int f = i & 63;
        int hp = i >> 6;                           // h*64+p
        ow2[i] = out_w[(size_t)f * 512 + hp];
        return;
    }
    __shared__ float t[64][20];
    int mat = blk >> 6;
    int dt8 = (blk >> 3) & 7;        // 16-row group of d
    int ct  = blk & 7;               // 64-col group
    const float* W = (mat == 0) ? Wq : (mat == 1) ? Wk : (mat == 2) ? Wv : Wr;
    int tid  = threadIdx.x;
    int col  = tid & 63;
    int row0 = tid >> 6;             // 0..3
    for (int i = 0; i < 4; i++) {
        int row = row0 + i * 4;      // 0..15 within d-group
        t[col][row] = W[(size_t)(dt8 * 16 + row) * 512 + ct * 64 + col];
    }
    __syncthreads();
    int wc  = tid & 63;
    int seg = tid >> 6;              // 0..3
    unsigned u = pack_fp8x4(t[wc][seg * 4 + 0] * W_SCALE, t[wc][seg * 4 + 1] * W_SCALE,
                            t[wc][seg * 4 + 2] * W_SCALE, t[wc][seg * 4 + 3] * W_SCALE);
    int d0 = dt8 * 16 + seg * 4;     // first d of this dword (d0..d0+3 share quad/ks)
    int q_ = (d0 >> 3) & 3, k_ = d0 >> 5, r_ = d0 & 7;
    *(unsigned*)&Wt[((size_t)mat * 512 + ct * 64 + wc) * 128 + q_ * 32 + k_ * 8 + r_] = u;
}

__global__ __launch_bounds__(256, 2) void autoint_kernel(
        const int* __restrict__ fidx,
        const float* __restrict__ emb,             // [100000][128]
        const unsigned char* __restrict__ Wt,      // fp8 [4][512][128] permuted, x W_SCALE
        const float* __restrict__ ow2,             // [8][64][64] transposed out_w
        const float* __restrict__ out_b,           // [1]
        float* __restrict__ y) {                   // [2048]
    // 64 KB: two 32-KB batch regions, each q|k|vT|att (4 x 4096 shorts).
    // Batch j's fp8 e staging (8 KB) overlays its q region in the prologue;
    // final red[] overlays q0 after the last phase2.
    __shared__ __align__(16) unsigned short smem[8 * 4096];
    unsigned char* smem8 = (unsigned char*)smem;

    const int b2   = blockIdx.x;          // handles batches 2*b2, 2*b2+1
    const int tid  = threadIdx.x;
    const int wave = tid >> 6;
    const int lane = tid & 63;
    const int quad = lane >> 4;
    const int ln16 = lane & 15;

    const int* idx0 = fidx + (size_t)(2 * b2) * 64;
    const int* idx1 = idx0 + 64;

    // ---- stage e for BOTH batches (fp32 -> fp8 x E_SCALE), A-frag order ----
    for (int it = 0; it < 8; it++) {
        int s  = tid + it * 256;          // 0..2047
        int j  = s >> 10;
        int ss = s & 1023;
        int tm = ss >> 8, ks = (ss >> 6) & 3, qd = (ss >> 4) & 3, m = ss & 15;
        int f  = tm * 16 + m;
        const int* idx = j ? idx1 : idx0;
        const float* src = emb + (size_t)idx[f] * 128 + ks * 32 + qd * 8;
        float4 lo = *(const float4*)src;
        float4 hi = *(const float4*)(src + 4);
        uint2 pk;
        pk.x = pack_fp8x4(lo.x * E_SCALE, lo.y * E_SCALE, lo.z * E_SCALE, lo.w * E_SCALE);
        pk.y = pack_fp8x4(hi.x * E_SCALE, hi.y * E_SCALE, hi.z * E_SCALE, hi.w * E_SCALE);
        *(uint2*)&smem8[j * 32768 + ss * 8] = pk;   // overlays batch j's q region
    }
    __syncthreads();

    // ---- hoist fp8 e A-fragments (both batches, 64 VGPRs) ----
    long long a[2][4][4];
#pragma unroll
    for (int j = 0; j < 2; j++)
        for (int tm = 0; tm < 4; tm++)
            for (int ks = 0; ks < 4; ks++)
                a[j][tm][ks] =
                    *(const long long*)&smem8[j * 32768 + ((tm * 4 + ks) * 64 + lane) * 8];
    __syncthreads();   // all A-reads done before phase1 overwrites q regions

    float acc_out[2] = {0.f, 0.f};

    // W fragment loader (SHARED by both batches): lane's 4 fragments for
    // (mat m, head h) are 32 contiguous bytes -> 2 b128 loads.
    auto loadW = [&](int m, int h, long long (&bf)[4]) {
        const unsigned char* WtM =
            Wt + ((size_t)m * 512 + h * 64 + wave * 16 + ln16) * 128 + quad * 32;
        llx2 w01 = *(const llx2*)WtM;
        llx2 w23 = *(const llx2*)(WtM + 16);
        bf[0] = w01[0]; bf[1] = w01[1]; bf[2] = w23[0]; bf[3] = w23[1];
    };

    // phase1_both: project q,k,vT for BOTH batches, tm-PAIRED: 4 independent
    // accumulator chains (j x t) share the W fragment bfm[m][ks] per step.
    auto phase1_both = [&](const long long (&bfm)[3][4]) {
        for (int m = 0; m < 3; m++) {
            for (int tp = 0; tp < 4; tp += 2) {
                f32x4 acc00 = {0.f, 0.f, 0.f, 0.f};   // [j=0][t=0]
                f32x4 acc10 = {0.f, 0.f, 0.f, 0.f};   // [j=1][t=0]
                f32x4 acc01 = {0.f, 0.f, 0.f, 0.f};   // [j=0][t=1]
                f32x4 acc11 = {0.f, 0.f, 0.f, 0.f};   // [j=1][t=1]
                __builtin_amdgcn_s_setprio(1);
                for (int ks = 0; ks < 4; ks++) {
                    acc00 = __builtin_amdgcn_mfma_f32_16x16x32_fp8_fp8(a[0][tp][ks],     bfm[m][ks], acc00, 0, 0, 0);
                    acc10 = __builtin_amdgcn_mfma_f32_16x16x32_fp8_fp8(a[1][tp][ks],     bfm[m][ks], acc10, 0, 0, 0);
                    acc01 = __builtin_amdgcn_mfma_f32_16x16x32_fp8_fp8(a[0][tp + 1][ks], bfm[m][ks], acc01, 0, 0, 0);
                    acc11 = __builtin_amdgcn_mfma_f32_16x16x32_fp8_fp8(a[1][tp + 1][ks], bfm[m][ks], acc11, 0, 0, 0);
                }
                __builtin_amdgcn_s_setprio(0);
                if (m == 0) {
                    for (int r = 0; r < 4; r++) {
                        QL(0)[SWZ(tp * 16 + quad * 4 + r, wave * 16 + ln16)]       = f2bf_t(acc00[r]);
                        QL(1)[SWZ(tp * 16 + quad * 4 + r, wave * 16 + ln16)]       = f2bf_t(acc10[r]);
                        QL(0)[SWZ((tp + 1) * 16 + quad * 4 + r, wave * 16 + ln16)] = f2bf_t(acc01[r]);
                        QL(1)[SWZ((tp + 1) * 16 + quad * 4 + r, wave * 16 + ln16)] = f2bf_t(acc11[r]);
                    }
                } else if (m == 1) {
                    for (int r = 0; r < 4; r++) {
                        KL(0)[SWZ(tp * 16 + quad * 4 + r, wave * 16 + ln16)]       = f2bf_t(acc00[r]);
                        KL(1)[SWZ(tp * 16 + quad * 4 + r, wave * 16 + ln16)]       = f2bf_t(acc10[r]);
                        KL(0)[SWZ((tp + 1) * 16 + quad * 4 + r, wave * 16 + ln16)] = f2bf_t(acc01[r]);
                        KL(1)[SWZ((tp + 1) * 16 + quad * 4 + r, wave * 16 + ln16)] = f2bf_t(acc11[r]);
                    }
                } else {
                    uint2 pk;
                    pk.x = pack_bf2(acc00[0], acc00[1]);
                    pk.y = pack_bf2(acc00[2], acc00[3]);
                    *(uint2*)&VTL(0)[SWZ(wave * 16 + ln16, tp * 16 + quad * 4)] = pk;
                    pk.x = pack_bf2(acc10[0], acc10[1]);
                    pk.y = pack_bf2(acc10[2], acc10[3]);
                    *(uint2*)&VTL(1)[SWZ(wave * 16 + ln16, tp * 16 + quad * 4)] = pk;
                    pk.x = pack_bf2(acc01[0], acc01[1]);
                    pk.y = pack_bf2(acc01[2], acc01[3]);
                    *(uint2*)&VTL(0)[SWZ(wave * 16 + ln16, (tp + 1) * 16 + quad * 4)] = pk;
                    pk.x = pack_bf2(acc11[0], acc11[1]);
                    pk.y = pack_bf2(acc11[2], acc11[3]);
                    *(uint2*)&VTL(1)[SWZ(wave * 16 + ln16, (tp + 1) * 16 + quad * 4)] = pk;
                }
            }
        }
    };

    // phase2_both: scores+softmax for BOTH batches, tm-PAIRED (4 chains).
    auto phase2_both = [&]() {
        float sc0[4][4], sc1[4][4];
        float sum0 = 0.f, sum1 = 0.f;
        for (int tp = 0; tp < 4; tp += 2) {
            f32x4 acc00 = {0.f, 0.f, 0.f, 0.f};
            f32x4 acc10 = {0.f, 0.f, 0.f, 0.f};
            f32x4 acc01 = {0.f, 0.f, 0.f, 0.f};
            f32x4 acc11 = {0.f, 0.f, 0.f, 0.f};
            __builtin_amdgcn_s_setprio(1);
            for (int ks = 0; ks < 2; ks++) {
                bf16x8 bb0 = *(const bf16x8*)&KL(0)[SWZ(wave * 16 + ln16, ks * 32 + quad * 8)];
                bf16x8 bb1 = *(const bf16x8*)&KL(1)[SWZ(wave * 16 + ln16, ks * 32 + quad * 8)];
                bf16x8 af00 = *(const bf16x8*)&QL(0)[SWZ(tp * 16 + ln16, ks * 32 + quad * 8)];
                bf16x8 af10 = *(const bf16x8*)&QL(1)[SWZ(tp * 16 + ln16, ks * 32 + quad * 8)];
                bf16x8 af01 = *(const bf16x8*)&QL(0)[SWZ((tp + 1) * 16 + ln16, ks * 32 + quad * 8)];
                bf16x8 af11 = *(const bf16x8*)&QL(1)[SWZ((tp + 1) * 16 + ln16, ks * 32 + quad * 8)];
                acc00 = __builtin_amdgcn_mfma_f32_16x16x32_bf16(af00, bb0, acc00, 0, 0, 0);
                acc10 = __builtin_amdgcn_mfma_f32_16x16x32_bf16(af10, bb1, acc10, 0, 0, 0);
                acc01 = __builtin_amdgcn_mfma_f32_16x16x32_bf16(af01, bb0, acc01, 0, 0, 0);
                acc11 = __builtin_amdgcn_mfma_f32_16x16x32_bf16(af11, bb1, acc11, 0, 0, 0);
            }
            __builtin_amdgcn_s_setprio(0);
            for (int r = 0; r < 4; r++) {
                float e00 = __expf(acc00[r] * INV_RAW2);
                float e10 = __expf(acc10[r] * INV_RAW2);
                float e01 = __expf(acc01[r] * INV_RAW2);
                float e11 = __expf(acc11[r] * INV_RAW2);
                sc0[tp][r] = e00;     sum0 += e00;
                sc1[tp][r] = e10;     sum1 += e10;
                sc0[tp + 1][r] = e01; sum0 += e01;
                sc1[tp + 1][r] = e11; sum1 += e11;
            }
        }
        // column (q-axis) reductions across quads, both batches
        sum0 += __shfl_xor(sum0, 16);
        sum1 += __shfl_xor(sum1, 16);
        sum0 += __shfl_xor(sum0, 32);
        sum1 += __shfl_xor(sum1, 32);
        float inv0 = 1.f / sum0;
        float inv1 = 1.f / sum1;
        for (int tm = 0; tm < 4; tm++)
            for (int r = 0; r < 4; r++) {
                ATL(0)[SWZ(tm * 16 + quad * 4 + r, wave * 16 + ln16)] =
                    f2bf_t(sc0[tm][r] * inv0);
                ATL(1)[SWZ(tm * 16 + quad * 4 + r, wave * 16 + ln16)] =
                    f2bf_t(sc1[tm][r] * inv1);
            }
    };

    {
        long long bfm[3][4];
        for (int m = 0; m < 3; m++) loadW(m, 0, bfm[m]);
        phase1_both(bfm);
    }
    __syncthreads();

    for (int h = 0; h < 8; h++) {
        phase2_both();
        __syncthreads();

        // ---- merged interval: [shared W loads] phase3(h)+r-proj, j fully
        //      interleaved (acc0/acc1 2-chains + racc0/racc1 4-chains = 4
        //      independent chains per tm) ; phase1_both(h+1). vT reads
        //      precede same-wave vT writes; q,k,att hazards cross barriers. ----
        {
            long long bfr[4];
            loadW(3, h, bfr);
            long long bfn[3][4];
            if (h < 7)
                for (int m = 0; m < 3; m++) loadW(m, h + 1, bfn[m]);
            const float* owr = ow2 + ((size_t)(h * 64 + wave * 16 + ln16)) * 64;
            for (int tm = 0; tm < 4; tm++) {
                float4 owv = *(const float4*)&owr[tm * 16 + quad * 4];
                f32x4 acc0 = {0.f, 0.f, 0.f, 0.f};
                f32x4 acc1 = {0.f, 0.f, 0.f, 0.f};
                f32x4 racc0 = {0.f, 0.f, 0.f, 0.f};
                f32x4 racc1 = {0.f, 0.f, 0.f, 0.f};
                __builtin_amdgcn_s_setprio(1);
                for (int ks = 0; ks < 2; ks++) {
                    bf16x8 af0 = *(const bf16x8*)&ATL(0)[SWZ(tm * 16 + ln16, ks * 32 + quad * 8)];
                    bf16x8 bb0 = *(const bf16x8*)&VTL(0)[SWZ(wave * 16 + ln16, ks * 32 + quad * 8)];
                    bf16x8 af1 = *(const bf16x8*)&ATL(1)[SWZ(tm * 16 + ln16, ks * 32 + quad * 8)];
                    bf16x8 bb1 = *(const bf16x8*)&VTL(1)[SWZ(wave * 16 + ln16, ks * 32 + quad * 8)];
                    acc0 = __builtin_amdgcn_mfma_f32_16x16x32_bf16(af0, bb0, acc0, 0, 0, 0);
                    acc1 = __builtin_amdgcn_mfma_f32_16x16x32_bf16(af1, bb1, acc1, 0, 0, 0);
                }
                for (int ks = 0; ks < 4; ks++) {
                    racc0 = __builtin_amdgcn_mfma_f32_16x16x32_fp8_fp8(a[0][tm][ks], bfr[ks], racc0, 0, 0, 0);
                    racc1 = __builtin_amdgcn_mfma_f32_16x16x32_fp8_fp8(a[1][tm][ks], bfr[ks], racc1, 0, 0, 0);
                }
                __builtin_amdgcn_s_setprio(0);
                // branchless relu
                acc_out[0] += fmaxf(acc0[0] + racc0[0], 0.f) * owv.x;
                acc_out[1] += fmaxf(acc1[0] + racc1[0], 0.f) * owv.x;
                acc_out[0] += fmaxf(acc0[1] + racc0[1], 0.f) * owv.y;
                acc_out[1] += fmaxf(acc1[1] + racc1[1], 0.f) * owv.y;
                acc_out[0] += fmaxf(acc0[2] + racc0[2], 0.f) * owv.z;
                acc_out[1] += fmaxf(acc1[2] + racc1[2], 0.f) * owv.z;
                acc_out[0] += fmaxf(acc0[3] + racc0[3], 0.f) * owv.w;
                acc_out[1] += fmaxf(acc1[3] + racc1[3], 0.f) * owv.w;
            }
            if (h < 7) phase1_both(bfn);
        }
        __syncthreads();
    }

    // ---- block reduction (per batch), undo raw scale, sigmoid ----
    // red[] overlays q0 (dead after h=7 phase2; final loop barrier orders).
    float* red = (float*)QL(0);
#pragma unroll
    for (int j = 0; j < 2; j++) {
        float v = acc_out[j];
        for (int off = 32; off >= 1; off >>= 1) v += __shfl_xor(v, off);
        if (lane == 0) red[j * 4 + wave] = v;
    }
    __syncthreads();
    if (tid < 2) {
        int j = tid;
        float s = (red[j * 4 + 0] + red[j * 4 + 1] + red[j * 4 + 2] + red[j * 4 + 3])
                      * INV_RAW + out_b[0];
        y[2 * b2 + j] = 1.f / (1.f + __expf(-s));
    }
}

// Fallback (no usable workspace): bf16 path, per-head strided W gather.
__global__ __launch_bounds__(256) void autoint_kernel_nows(
        const int* __restrict__ fidx,
        const float* __restrict__ emb,
        const float* __restrict__ W0, const float* __restrict__ W1,
        const float* __restrict__ W2, const float* __restrict__ W3,
        const float* __restrict__ out_w, const float* __restrict__ out_b,
        float* __restrict__ y) {
    __shared__ __align__(16) unsigned short escratch[64 * 128];
    __shared__ __align__(16) unsigned short q_lds[64 * LDP];
    __shared__ __align__(16) unsigned short k_lds[64 * LDP];
    __shared__ __align__(16) unsigned short vT_lds[64 * LDP];
    __shared__ float red[4];

    const int b    = blockIdx.x;
    const int tid  = threadIdx.x;
    const int wave = tid >> 6;
    const int lane = tid & 63;
    const int quad = lane >> 4;
    const int ln16 = lane & 15;
    const int* idx = fidx + b * 64;

    for (int it = 0; it < 4; it++) {
        int s  = tid + it * 256;
        int tm = s >> 8, ks = (s >> 6) & 3, qd = (s >> 4) & 3, m = s & 15;
        int f  = tm * 16 + m;
        const float* src = emb + (size_t)idx[f] * 128 + ks * 32 + qd * 8;
        float4 lo = *(const float4*)src;
        float4 hi = *(const float4*)(src + 4);
        uint4 pk;
        pk.x = pack_bf2(lo.x, lo.y); pk.y = pack_bf2(lo.z, lo.w);
        pk.z = pack_bf2(hi.x, hi.y); pk.w = pack_bf2(hi.z, hi.w);
        *(uint4*)&escratch[s * 8] = pk;
    }
    __syncthreads();

    bf16x8 a[4][4];
    for (int tm = 0; tm < 4; tm++)
        for (int ks = 0; ks < 4; ks++)
            a[tm][ks] = *(const bf16x8*)&escratch[((tm * 4 + ks) * 64 + lane) * 8];
    unsigned short* att_lds = escratch;

    float acc_out = 0.f;
    f32x4 r_reg[4];

    for (int h = 0; h < 8; h++) {
        for (int m = 0; m < 4; m++) {
            const float* Wsel = (m == 0) ? W0 : (m == 1) ? W1 : (m == 2) ? W2 : W3;
            bf16x8 bf[4];
            for (int ks = 0; ks < 4; ks++) {
                union { unsigned short u[8]; bf16x8 v; } p;
                const float* base = Wsel + (size_t)(ks * 32 + quad * 8) * 512
                                    + h * 64 + wave * 16 + ln16;
                for (int j = 0; j < 8; j++) p.u[j] = f2bf(base[(size_t)j * 512]);
                bf[ks] = p.v;
            }
            for (int tm = 0; tm < 4; tm++) {
                f32x4 acc = {0.f, 0.f, 0.f, 0.f};
                for (int ks = 0; ks < 4; ks++)
                    acc = __builtin_amdgcn_mfma_f32_16x16x32_bf16(a[tm][ks], bf[ks], acc, 0, 0, 0);
                if (m == 0) {
                    for (int r = 0; r < 4; r++)
                        q_lds[(tm * 16 + quad * 4 + r) * LDP + wave * 16 + ln16] = f2bf_t(acc[r]);
                } else if (m == 1) {
                    for (int r = 0; r < 4; r++)
                        k_lds[(tm * 16 + quad * 4 + r) * LDP + wave * 16 + ln16] = f2bf_t(acc[r]);
                } else if (m == 2) {
                    uint2 pk;
                    pk.x = pack_bf2(acc[0], acc[1]);
                    pk.y = pack_bf2(acc[2], acc[3]);
                    *(uint2*)&vT_lds[(wave * 16 + ln16) * LDP + tm * 16 + quad * 4] = pk;
                } else {
                    r_reg[tm] = acc;
                }
            }
        }
        __syncthreads();
        {
            float sc[4][4];
            float sum = 0.f;
            for (int tm = 0; tm < 4; tm++) {
                f32x4 acc = {0.f, 0.f, 0.f, 0.f};
                for (int ks = 0; ks < 2; ks++) {
                    bf16x8 af = *(const bf16x8*)&q_lds[(tm * 16 + ln16) * LDP + ks * 32 + quad * 8];
                    bf16x8 bb = *(const bf16x8*)&k_lds[(wave * 16 + ln16) * LDP + ks * 32 + quad * 8];
                    acc = __builtin_amdgcn_mfma_f32_16x16x32_bf16(af, bb, acc, 0, 0, 0);
                }
                for (int r = 0; r < 4; r++) {
                    float e = __expf(acc[r]);
                    sc[tm][r] = e;
                    sum += e;
                }
            }
            sum += __shfl_xor(sum, 16);
            sum += __shfl_xor(sum, 32);
            float inv = 1.f / sum;
            for (int tm = 0; tm < 4; tm++)
                for (int r = 0; r < 4; r++)
                    att_lds[(tm * 16 + quad * 4 + r) * LDP + wave * 16 + ln16] =
                        f2bf_t(sc[tm][r] * inv);
        }
        __syncthreads();
        {
            const float* ow = out_w + h * 64 + wave * 16;
            for (int tm = 0; tm < 4; tm++) {
                f32x4 acc = {0.f, 0.f, 0.f, 0.f};
                for (int ks = 0; ks < 2; ks++) {
                    bf16x8 af = *(const bf16x8*)&att_lds[(tm * 16 + ln16) * LDP + ks * 32 + quad * 8];
                    bf16x8 bb = *(const bf16x8*)&vT_lds[(wave * 16 + ln16) * LDP + ks * 32 + quad * 8];
                    acc = __builtin_amdgcn_mfma_f32_16x16x32_bf16(af, bb, acc, 0, 0, 0);
                }
                for (int r = 0; r < 4; r++) {
                    int f = tm * 16 + quad * 4 + r;
                    float mval = acc[r] + r_reg[tm][r];
                    if (mval > 0.f) acc_out += mval * ow[(size_t)f * 512 + ln16];
                }
            }
        }
        __syncthreads();
    }
    for (int off = 32; off >= 1; off >>= 1) acc_out += __shfl_xor(acc_out, off);
    if (lane == 0) red[wave] = acc_out;
    __syncthreads();
    if (tid == 0) {
        float s = red[0] + red[1] + red[2] + red[3] + out_b[0];
        y[b] = 1.f / (1.f + __expf(-s));
    }
}

extern "C" void kernel_launch(void* const* d_in, const int* in_sizes, int n_in,
                              void* d_out, int out_size, void* d_ws, size_t ws_size,
                              hipStream_t stream) {
    (void)in_sizes; (void)n_in; (void)out_size;
    const int*   fidx = (const int*)d_in[0];
    const float* emb  = (const float*)d_in[1];
    const float* Wq   = (const float*)d_in[2];
    const float* Wk   = (const float*)d_in[3];
    const float* Wv   = (const float*)d_in[4];
    const float* Wr   = (const float*)d_in[5];
    const float* ow   = (const float*)d_in[6];
    const float* ob   = (const float*)d_in[7];
    float*       yy   = (float*)d_out;

    const size_t wt_bytes  = (size_t)4 * 512 * 128;   // 256 KB (fp8 W, permuted)
    const size_t ow2_bytes = (size_t)8 * 64 * 64 * 4; // 128 KB (transposed out_w)
    if (d_ws != nullptr && ws_size >= wt_bytes + ow2_bytes) {
        unsigned char* Wt  = (unsigned char*)d_ws;
        float*         ow2 = (float*)((unsigned char*)d_ws + wt_bytes);
        prep_w<<<384, 256, 0, stream>>>(Wq, Wk, Wv, Wr, ow, Wt, ow2);
        autoint_kernel<<<1024, 256, 0, stream>>>(fidx, emb, Wt, ow2, ob, yy);
    } else {
        autoint_kernel_nows<<<2048, 256, 0, stream>>>(fidx, emb, Wq, Wk, Wv, Wr, ow, ob, yy);
    }
}

// Round 13
// 186.772 us; speedup vs baseline: 1.1205x; 1.0025x over previous
//
#include <hip/hip_runtime.h>
#include <hip/hip_bf16.h>
#include <hip/hip_fp8.h>
#include <stdint.h>

// AutoInt: B=2048, F=64, D=128, H=8, P=64, V=100000 -- FP32 in/out.
// R13 = R11 verbatim (proven optimum). 2 batches/block (grid 1024), 4
// waves, (256,2); the two batches' chains interleaved at INSTRUCTION
// granularity: phase1_both pairs mfma(a[0],W) with mfma(a[1],W) (shared B
// operand), phase2_both alternates the batches' LDS loads/MFMAs/exp chains.
//
// Ledger: R0 180us. R1 (256,5) spill+LDS dead end. R2/R3 SWZ (conflicts
// 6.29M->1.05M) cancelled by spill. R4 GA 455us. R5 r-proj in phase3 ->
// 174.5. R6 [fused prep + W-b128 + setprio] -> 138.9. R7 (256,2) no spill
// -> 127.4. R8 (256,3): HW wave slots quantize at 128/256 regs -> neutral.
// R9 coarse 2-batch fusion -> 125.5. R10 LDS-resident A-frags (3 blk/CU,
// 39% occ) -> 133.5 REGRESSION (waves lose to added LDS traffic). R11
// instruction-granular 2-chain interleave -> 109.8 (best). R12 chain-width
// 4 -> 122.1 REGRESSION (LDS store/load bursts + worse static schedule;
// 2 chains is the sweet spot). Axes occupancy/registers/work-per-wave/
// chain-width all probed both directions; R11 is the design-space optimum.

typedef __attribute__((ext_vector_type(8))) __bf16 bf16x8;
typedef __attribute__((ext_vector_type(4))) float f32x4;
typedef __attribute__((ext_vector_type(2))) long long llx2;

#define LDP 72            // padded row stride (shorts) -- fallback kernel only
#define E_SCALE 64.0f     // e -> fp8 pre-scale
#define W_SCALE 8.0f      // W -> fp8 pre-scale
#define INV_RAW (1.0f / 512.0f)            // undo E_SCALE*W_SCALE
#define INV_RAW2 (1.0f / (512.0f * 512.0f))  // undo (E*W)^2 in scores

// swizzled [64][64] short-index; involution applied on both write and read.
// Measured (R1): bank conflicts 6.29M -> 1.05M vs the LDP=72 pad.
#define SWZ(row, col) (((row) * 64) + ((col) ^ (((row) & 7) << 3)))

// per-batch LDS regions (shorts): batch j owns 16384 shorts (32 KB)
#define QL(j)  (smem + (j) * 16384)
#define KL(j)  (smem + (j) * 16384 + 4096)
#define VTL(j) (smem + (j) * 16384 + 8192)
#define ATL(j) (smem + (j) * 16384 + 12288)

// RNE f2bf (prep/fallback only)
__device__ inline unsigned short f2bf(float f) {
    unsigned u = __float_as_uint(f);
    return (unsigned short)((u + 0x7fff + ((u >> 16) & 1)) >> 16);
}
// truncating f2bf for LDS scatters (<=0.39% one-sided rel err on intermediates)
__device__ inline unsigned short f2bf_t(float f) {
    return (unsigned short)(__float_as_uint(f) >> 16);
}
// pack two f32 -> two bf16 in one dword (lo=a, hi=b)
__device__ inline unsigned pack_bf2(float a, float b) {
#if __has_builtin(__builtin_amdgcn_cvt_pk_bf16_f32)
    typedef __attribute__((ext_vector_type(2))) __bf16 bf16x2;
    bf16x2 r = __builtin_amdgcn_cvt_pk_bf16_f32(a, b);
    return *(unsigned*)&r;
#else
    return (__float_as_uint(a) >> 16) | (__float_as_uint(b) & 0xFFFF0000u);
#endif
}
// pack 4 f32 -> 4 fp8 e4m3 bytes in one dword
__device__ inline unsigned pack_fp8x4(float a, float b, float c, float d) {
#if __has_builtin(__builtin_amdgcn_cvt_pk_fp8_f32)
    int u = __builtin_amdgcn_cvt_pk_fp8_f32(a, b, 0, false);
    u = __builtin_amdgcn_cvt_pk_fp8_f32(c, d, u, true);
    return (unsigned)u;
#else
    __hip_fp8_e4m3 qa(a), qb(b), qc(c), qd(d);
    return (unsigned)qa.__x | ((unsigned)qb.__x << 8) |
           ((unsigned)qc.__x << 16) | ((unsigned)qd.__x << 24);
#endif
}

// ---- fused prep ----
// blocks 0..255: transpose+convert W fp32 [128][512] -> fp8 Wt[4][512][...]
//   with PERMUTED inner layout: byte for dim d lands at quad*32 + ks*8 + r
//   (quad=(d>>3)&3, ks=d>>5, r=d&7) -- a lane's 4 MFMA fragments are 32
//   contiguous bytes -> 2 b128 loads.
// blocks 256..383: transpose out_w [32768] -> ow2[h*64+p][f] (128 KB).
__global__ __launch_bounds__(256) void prep_w(
        const float* __restrict__ Wq, const float* __restrict__ Wk,
        const float* __restrict__ Wv, const float* __restrict__ Wr,
        const float* __restrict__ out_w,
        unsigned char* __restrict__ Wt, float* __restrict__ ow2) {
    int blk = blockIdx.x;
    if (blk >= 256) {
        int i = (blk - 256) * 256 + threadIdx.x;   // 0..32767
        int f = i & 63;
        int hp = i >> 6;                           // h*64+p
        ow2[i] = out_w[(size_t)f * 512 + hp];
        return;
    }
    __shared__ float t[64][20];
    int mat = blk >> 6;
    int dt8 = (blk >> 3) & 7;        // 16-row group of d
    int ct  = blk & 7;               // 64-col group
    const float* W = (mat == 0) ? Wq : (mat == 1) ? Wk : (mat == 2) ? Wv : Wr;
    int tid  = threadIdx.x;
    int col  = tid & 63;
    int row0 = tid >> 6;             // 0..3
    for (int i = 0; i < 4; i++) {
        int row = row0 + i * 4;      // 0..15 within d-group
        t[col][row] = W[(size_t)(dt8 * 16 + row) * 512 + ct * 64 + col];
    }
    __syncthreads();
    int wc  = tid & 63;
    int seg = tid >> 6;              // 0..3
    unsigned u = pack_fp8x4(t[wc][seg * 4 + 0] * W_SCALE, t[wc][seg * 4 + 1] * W_SCALE,
                            t[wc][seg * 4 + 2] * W_SCALE, t[wc][seg * 4 + 3] * W_SCALE);
    int d0 = dt8 * 16 + seg * 4;     // first d of this dword (d0..d0+3 share quad/ks)
    int q_ = (d0 >> 3) & 3, k_ = d0 >> 5, r_ = d0 & 7;
    *(unsigned*)&Wt[((size_t)mat * 512 + ct * 64 + wc) * 128 + q_ * 32 + k_ * 8 + r_] = u;
}

__global__ __launch_bounds__(256, 2) void autoint_kernel(
        const int* __restrict__ fidx,
        const float* __restrict__ emb,             // [100000][128]
        const unsigned char* __restrict__ Wt,      // fp8 [4][512][128] permuted, x W_SCALE
        const float* __restrict__ ow2,             // [8][64][64] transposed out_w
        const float* __restrict__ out_b,           // [1]
        float* __restrict__ y) {                   // [2048]
    // 64 KB: two 32-KB batch regions, each q|k|vT|att (4 x 4096 shorts).
    // Batch j's fp8 e staging (8 KB) overlays its q region in the prologue;
    // final red[] overlays q0 after the last phase2.
    __shared__ __align__(16) unsigned short smem[8 * 4096];
    unsigned char* smem8 = (unsigned char*)smem;

    const int b2   = blockIdx.x;          // handles batches 2*b2, 2*b2+1
    const int tid  = threadIdx.x;
    const int wave = tid >> 6;
    const int lane = tid & 63;
    const int quad = lane >> 4;
    const int ln16 = lane & 15;

    const int* idx0 = fidx + (size_t)(2 * b2) * 64;
    const int* idx1 = idx0 + 64;

    // ---- stage e for BOTH batches (fp32 -> fp8 x E_SCALE), A-frag order ----
    for (int it = 0; it < 8; it++) {
        int s  = tid + it * 256;          // 0..2047
        int j  = s >> 10;
        int ss = s & 1023;
        int tm = ss >> 8, ks = (ss >> 6) & 3, qd = (ss >> 4) & 3, m = ss & 15;
        int f  = tm * 16 + m;
        const int* idx = j ? idx1 : idx0;
        const float* src = emb + (size_t)idx[f] * 128 + ks * 32 + qd * 8;
        float4 lo = *(const float4*)src;
        float4 hi = *(const float4*)(src + 4);
        uint2 pk;
        pk.x = pack_fp8x4(lo.x * E_SCALE, lo.y * E_SCALE, lo.z * E_SCALE, lo.w * E_SCALE);
        pk.y = pack_fp8x4(hi.x * E_SCALE, hi.y * E_SCALE, hi.z * E_SCALE, hi.w * E_SCALE);
        *(uint2*)&smem8[j * 32768 + ss * 8] = pk;   // overlays batch j's q region
    }
    __syncthreads();

    // ---- hoist fp8 e A-fragments (both batches, 64 VGPRs) ----
    long long a[2][4][4];
#pragma unroll
    for (int j = 0; j < 2; j++)
        for (int tm = 0; tm < 4; tm++)
            for (int ks = 0; ks < 4; ks++)
                a[j][tm][ks] =
                    *(const long long*)&smem8[j * 32768 + ((tm * 4 + ks) * 64 + lane) * 8];
    __syncthreads();   // all A-reads done before phase1 overwrites q regions

    float acc_out[2] = {0.f, 0.f};

    // W fragment loader (SHARED by both batches): lane's 4 fragments for
    // (mat m, head h) are 32 contiguous bytes -> 2 b128 loads.
    auto loadW = [&](int m, int h, long long (&bf)[4]) {
        const unsigned char* WtM =
            Wt + ((size_t)m * 512 + h * 64 + wave * 16 + ln16) * 128 + quad * 32;
        llx2 w01 = *(const llx2*)WtM;
        llx2 w23 = *(const llx2*)(WtM + 16);
        bf[0] = w01[0]; bf[1] = w01[1]; bf[2] = w23[0]; bf[3] = w23[1];
    };

    // phase1_both: project p-slice [wave*16,+16) of q,k,vT for BOTH batches,
    // interleaved at the ks level: each dependent-chain step of batch 0 has
    // batch 1's independent MFMA adjacent (shared B operand bfm[m][ks]).
    auto phase1_both = [&](const long long (&bfm)[3][4]) {
        for (int m = 0; m < 3; m++) {
            for (int tm = 0; tm < 4; tm++) {
                f32x4 acc0 = {0.f, 0.f, 0.f, 0.f};
                f32x4 acc1 = {0.f, 0.f, 0.f, 0.f};
                __builtin_amdgcn_s_setprio(1);
                for (int ks = 0; ks < 4; ks++) {
                    acc0 = __builtin_amdgcn_mfma_f32_16x16x32_fp8_fp8(a[0][tm][ks], bfm[m][ks], acc0, 0, 0, 0);
                    acc1 = __builtin_amdgcn_mfma_f32_16x16x32_fp8_fp8(a[1][tm][ks], bfm[m][ks], acc1, 0, 0, 0);
                }
                __builtin_amdgcn_s_setprio(0);
                if (m == 0) {
                    for (int r = 0; r < 4; r++) {
                        QL(0)[SWZ(tm * 16 + quad * 4 + r, wave * 16 + ln16)] = f2bf_t(acc0[r]);
                        QL(1)[SWZ(tm * 16 + quad * 4 + r, wave * 16 + ln16)] = f2bf_t(acc1[r]);
                    }
                } else if (m == 1) {
                    for (int r = 0; r < 4; r++) {
                        KL(0)[SWZ(tm * 16 + quad * 4 + r, wave * 16 + ln16)] = f2bf_t(acc0[r]);
                        KL(1)[SWZ(tm * 16 + quad * 4 + r, wave * 16 + ln16)] = f2bf_t(acc1[r]);
                    }
                } else {
                    uint2 pk0, pk1;
                    pk0.x = pack_bf2(acc0[0], acc0[1]);
                    pk0.y = pack_bf2(acc0[2], acc0[3]);
                    pk1.x = pack_bf2(acc1[0], acc1[1]);
                    pk1.y = pack_bf2(acc1[2], acc1[3]);
                    // wave-private rows w*16..w*16+15
                    *(uint2*)&VTL(0)[SWZ(wave * 16 + ln16, tm * 16 + quad * 4)] = pk0;
                    *(uint2*)&VTL(1)[SWZ(wave * 16 + ln16, tm * 16 + quad * 4)] = pk1;
                }
            }
        }
    };

    // phase2_both: scores+softmax for BOTH batches, interleaved per tm so
    // batch 1's LDS loads/MFMAs overlap batch 0's exp chain and vice versa.
    auto phase2_both = [&]() {
        float sc0[4][4], sc1[4][4];
        float sum0 = 0.f, sum1 = 0.f;
        for (int tm = 0; tm < 4; tm++) {
            f32x4 acc0 = {0.f, 0.f, 0.f, 0.f};
            f32x4 acc1 = {0.f, 0.f, 0.f, 0.f};
            __builtin_amdgcn_s_setprio(1);
            for (int ks = 0; ks < 2; ks++) {
                bf16x8 af0 = *(const bf16x8*)&QL(0)[SWZ(tm * 16 + ln16, ks * 32 + quad * 8)];
                bf16x8 bb0 = *(const bf16x8*)&KL(0)[SWZ(wave * 16 + ln16, ks * 32 + quad * 8)];
                bf16x8 af1 = *(const bf16x8*)&QL(1)[SWZ(tm * 16 + ln16, ks * 32 + quad * 8)];
                bf16x8 bb1 = *(const bf16x8*)&KL(1)[SWZ(wave * 16 + ln16, ks * 32 + quad * 8)];
                acc0 = __builtin_amdgcn_mfma_f32_16x16x32_bf16(af0, bb0, acc0, 0, 0, 0);
                acc1 = __builtin_amdgcn_mfma_f32_16x16x32_bf16(af1, bb1, acc1, 0, 0, 0);
            }
            __builtin_amdgcn_s_setprio(0);
            for (int r = 0; r < 4; r++) {
                float e0 = __expf(acc0[r] * INV_RAW2);
                float e1 = __expf(acc1[r] * INV_RAW2);
                sc0[tm][r] = e0; sum0 += e0;
                sc1[tm][r] = e1; sum1 += e1;
            }
        }
        // column (q-axis) reductions across quads, both batches
        sum0 += __shfl_xor(sum0, 16);
        sum1 += __shfl_xor(sum1, 16);
        sum0 += __shfl_xor(sum0, 32);
        sum1 += __shfl_xor(sum1, 32);
        float inv0 = 1.f / sum0;
        float inv1 = 1.f / sum1;
        for (int tm = 0; tm < 4; tm++)
            for (int r = 0; r < 4; r++) {
                ATL(0)[SWZ(tm * 16 + quad * 4 + r, wave * 16 + ln16)] =
                    f2bf_t(sc0[tm][r] * inv0);
                ATL(1)[SWZ(tm * 16 + quad * 4 + r, wave * 16 + ln16)] =
                    f2bf_t(sc1[tm][r] * inv1);
            }
    };

    {
        long long bfm[3][4];
        for (int m = 0; m < 3; m++) loadW(m, 0, bfm[m]);
        phase1_both(bfm);
    }
    __syncthreads();

    for (int h = 0; h < 8; h++) {
        phase2_both();
        __syncthreads();

        // ---- merged interval: [shared W loads] phase3(h)+r-proj x2 (already
        //      j-interleaved) ; phase1_both(h+1). vT reads precede same-wave
        //      vT writes; q,k,att hazards cross the surrounding barriers. ----
        {
            long long bfr[4];
            loadW(3, h, bfr);
            long long bfn[3][4];
            if (h < 7)
                for (int m = 0; m < 3; m++) loadW(m, h + 1, bfn[m]);
            const float* owr = ow2 + ((size_t)(h * 64 + wave * 16 + ln16)) * 64;
            for (int tm = 0; tm < 4; tm++) {
                float4 owv = *(const float4*)&owr[tm * 16 + quad * 4];
#pragma unroll
                for (int j = 0; j < 2; j++) {
                    const unsigned short* att_lds = ATL(j);
                    const unsigned short* vT_lds  = VTL(j);
                    f32x4 acc = {0.f, 0.f, 0.f, 0.f};
                    f32x4 racc = {0.f, 0.f, 0.f, 0.f};
                    __builtin_amdgcn_s_setprio(1);
                    for (int ks = 0; ks < 2; ks++) {
                        bf16x8 af = *(const bf16x8*)&att_lds[SWZ(tm * 16 + ln16, ks * 32 + quad * 8)];
                        bf16x8 bb = *(const bf16x8*)&vT_lds[SWZ(wave * 16 + ln16, ks * 32 + quad * 8)];
                        acc = __builtin_amdgcn_mfma_f32_16x16x32_bf16(af, bb, acc, 0, 0, 0);
                    }
                    for (int ks = 0; ks < 4; ks++)
                        racc = __builtin_amdgcn_mfma_f32_16x16x32_fp8_fp8(a[j][tm][ks], bfr[ks], racc, 0, 0, 0);
                    __builtin_amdgcn_s_setprio(0);
                    // branchless relu
                    acc_out[j] += fmaxf(acc[0] + racc[0], 0.f) * owv.x;
                    acc_out[j] += fmaxf(acc[1] + racc[1], 0.f) * owv.y;
                    acc_out[j] += fmaxf(acc[2] + racc[2], 0.f) * owv.z;
                    acc_out[j] += fmaxf(acc[3] + racc[3], 0.f) * owv.w;
                }
            }
            if (h < 7) phase1_both(bfn);
        }
        __syncthreads();
    }

    // ---- block reduction (per batch), undo raw scale, sigmoid ----
    // red[] overlays q0 (dead after h=7 phase2; final loop barrier orders).
    float* red = (float*)QL(0);
#pragma unroll
    for (int j = 0; j < 2; j++) {
        float v = acc_out[j];
        for (int off = 32; off >= 1; off >>= 1) v += __shfl_xor(v, off);
        if (lane == 0) red[j * 4 + wave] = v;
    }
    __syncthreads();
    if (tid < 2) {
        int j = tid;
        float s = (red[j * 4 + 0] + red[j * 4 + 1] + red[j * 4 + 2] + red[j * 4 + 3])
                      * INV_RAW + out_b[0];
        y[2 * b2 + j] = 1.f / (1.f + __expf(-s));
    }
}

// Fallback (no usable workspace): bf16 path, per-head strided W gather.
__global__ __launch_bounds__(256) void autoint_kernel_nows(
        const int* __restrict__ fidx,
        const float* __restrict__ emb,
        const float* __restrict__ W0, const float* __restrict__ W1,
        const float* __restrict__ W2, const float* __restrict__ W3,
        const float* __restrict__ out_w, const float* __restrict__ out_b,
        float* __restrict__ y) {
    __shared__ __align__(16) unsigned short escratch[64 * 128];
    __shared__ __align__(16) unsigned short q_lds[64 * LDP];
    __shared__ __align__(16) unsigned short k_lds[64 * LDP];
    __shared__ __align__(16) unsigned short vT_lds[64 * LDP];
    __shared__ float red[4];

    const int b    = blockIdx.x;
    const int tid  = threadIdx.x;
    const int wave = tid >> 6;
    const int lane = tid & 63;
    const int quad = lane >> 4;
    const int ln16 = lane & 15;
    const int* idx = fidx + b * 64;

    for (int it = 0; it < 4; it++) {
        int s  = tid + it * 256;
        int tm = s >> 8, ks = (s >> 6) & 3, qd = (s >> 4) & 3, m = s & 15;
        int f  = tm * 16 + m;
        const float* src = emb + (size_t)idx[f] * 128 + ks * 32 + qd * 8;
        float4 lo = *(const float4*)src;
        float4 hi = *(const float4*)(src + 4);
        uint4 pk;
        pk.x = pack_bf2(lo.x, lo.y); pk.y = pack_bf2(lo.z, lo.w);
        pk.z = pack_bf2(hi.x, hi.y); pk.w = pack_bf2(hi.z, hi.w);
        *(uint4*)&escratch[s * 8] = pk;
    }
    __syncthreads();

    bf16x8 a[4][4];
    for (int tm = 0; tm < 4; tm++)
        for (int ks = 0; ks < 4; ks++)
            a[tm][ks] = *(const bf16x8*)&escratch[((tm * 4 + ks) * 64 + lane) * 8];
    unsigned short* att_lds = escratch;

    float acc_out = 0.f;
    f32x4 r_reg[4];

    for (int h = 0; h < 8; h++) {
        for (int m = 0; m < 4; m++) {
            const float* Wsel = (m == 0) ? W0 : (m == 1) ? W1 : (m == 2) ? W2 : W3;
            bf16x8 bf[4];
            for (int ks = 0; ks < 4; ks++) {
                union { unsigned short u[8]; bf16x8 v; } p;
                const float* base = Wsel + (size_t)(ks * 32 + quad * 8) * 512
                                    + h * 64 + wave * 16 + ln16;
                for (int j = 0; j < 8; j++) p.u[j] = f2bf(base[(size_t)j * 512]);
                bf[ks] = p.v;
            }
            for (int tm = 0; tm < 4; tm++) {
                f32x4 acc = {0.f, 0.f, 0.f, 0.f};
                for (int ks = 0; ks < 4; ks++)
                    acc = __builtin_amdgcn_mfma_f32_16x16x32_bf16(a[tm][ks], bf[ks], acc, 0, 0, 0);
                if (m == 0) {
                    for (int r = 0; r < 4; r++)
                        q_lds[(tm * 16 + quad * 4 + r) * LDP + wave * 16 + ln16] = f2bf_t(acc[r]);
                } else if (m == 1) {
                    for (int r = 0; r < 4; r++)
                        k_lds[(tm * 16 + quad * 4 + r) * LDP + wave * 16 + ln16] = f2bf_t(acc[r]);
                } else if (m == 2) {
                    uint2 pk;
                    pk.x = pack_bf2(acc[0], acc[1]);
                    pk.y = pack_bf2(acc[2], acc[3]);
                    *(uint2*)&vT_lds[(wave * 16 + ln16) * LDP + tm * 16 + quad * 4] = pk;
                } else {
                    r_reg[tm] = acc;
                }
            }
        }
        __syncthreads();
        {
            float sc[4][4];
            float sum = 0.f;
            for (int tm = 0; tm < 4; tm++) {
                f32x4 acc = {0.f, 0.f, 0.f, 0.f};
                for (int ks = 0; ks < 2; ks++) {
                    bf16x8 af = *(const bf16x8*)&q_lds[(tm * 16 + ln16) * LDP + ks * 32 + quad * 8];
                    bf16x8 bb = *(const bf16x8*)&k_lds[(wave * 16 + ln16) * LDP + ks * 32 + quad * 8];
                    acc = __builtin_amdgcn_mfma_f32_16x16x32_bf16(af, bb, acc, 0, 0, 0);
                }
                for (int r = 0; r < 4; r++) {
                    float e = __expf(acc[r]);
                    sc[tm][r] = e;
                    sum += e;
                }
            }
            sum += __shfl_xor(sum, 16);
            sum += __shfl_xor(sum, 32);
            float inv = 1.f / sum;
            for (int tm = 0; tm < 4; tm++)
                for (int r = 0; r < 4; r++)
                    att_lds[(tm * 16 + quad * 4 + r) * LDP + wave * 16 + ln16] =
                        f2bf_t(sc[tm][r] * inv);
        }
        __syncthreads();
        {
            const float* ow = out_w + h * 64 + wave * 16;
            for (int tm = 0; tm < 4; tm++) {
                f32x4 acc = {0.f, 0.f, 0.f, 0.f};
                for (int ks = 0; ks < 2; ks++) {
                    bf16x8 af = *(const bf16x8*)&att_lds[(tm * 16 + ln16) * LDP + ks * 32 + quad * 8];
                    bf16x8 bb = *(const bf16x8*)&vT_lds[(wave * 16 + ln16) * LDP + ks * 32 + quad * 8];
                    acc = __builtin_amdgcn_mfma_f32_16x16x32_bf16(af, bb, acc, 0, 0, 0);
                }
                for (int r = 0; r < 4; r++) {
                    int f = tm * 16 + quad * 4 + r;
                    float mval = acc[r] + r_reg[tm][r];
                    if (mval > 0.f) acc_out += mval * ow[(size_t)f * 512 + ln16];
                }
            }
        }
        __syncthreads();
    }
    for (int off = 32; off >= 1; off >>= 1) acc_out += __shfl_xor(acc_out, off);
    if (lane == 0) red[wave] = acc_out;
    __syncthreads();
    if (tid == 0) {
        float s = red[0] + red[1] + red[2] + red[3] + out_b[0];
        y[b] = 1.f / (1.f + __expf(-s));
    }
}

extern "C" void kernel_launch(void* const* d_in, const int* in_sizes, int n_in,
                              void* d_out, int out_size, void* d_ws, size_t ws_size,
                              hipStream_t stream) {
    (void)in_sizes; (void)n_in; (void)out_size;
    const int*   fidx = (const int*)d_in[0];
    const float* emb  = (const float*)d_in[1];
    const float* Wq   = (const float*)d_in[2];
    const float* Wk   = (const float*)d_in[3];
    const float* Wv   = (const float*)d_in[4];
    const float* Wr   = (const float*)d_in[5];
    const float* ow   = (const float*)d_in[6];
    const float* ob   = (const float*)d_in[7];
    float*       yy   = (float*)d_out;

    const size_t wt_bytes  = (size_t)4 * 512 * 128;   // 256 KB (fp8 W, permuted)
    const size_t ow2_bytes = (size_t)8 * 64 * 64 * 4; // 128 KB (transposed out_w)
    if (d_ws != nullptr && ws_size >= wt_bytes + ow2_bytes) {
        unsigned char* Wt  = (unsigned char*)d_ws;
        float*         ow2 = (float*)((unsigned char*)d_ws + wt_bytes);
        prep_w<<<384, 256, 0, stream>>>(Wq, Wk, Wv, Wr, ow, Wt, ow2);
        autoint_kernel<<<1024, 256, 0, stream>>>(fidx, emb, Wt, ow2, ob, yy);
    } else {
        autoint_kernel_nows<<<2048, 256, 0, stream>>>(fidx, emb, Wq, Wk, Wv, Wr, ow, ob, yy);
    }
}